// Round 9
// baseline (473.118 us; speedup 1.0000x reference)
//
#include <hip/hip_runtime.h>
#include <stdint.h>

#define S_LEN 2048
#define BATCH 2
#define HIDDEN 2560
#define NH 8
#define NKV 4
#define HD 256
#define QSZ (NH*HD)          // 2048
#define NQKV 4096            // QSZ + 2*KVSZ
#define MROWS (BATCH*S_LEN)  // 4096
#define SCALE_ATT 0.0625f

using bf16x8 = __attribute__((__ext_vector_type__(8))) __bf16;
using f32x4  = __attribute__((__ext_vector_type__(4))) float;
using s16x8  = __attribute__((__ext_vector_type__(8))) short;

union B8u { s16x8 s; bf16x8 b; };
union I4B8 { int4 i; bf16x8 b; };

__device__ __forceinline__ unsigned short f2bf(float x){
  unsigned u = __float_as_uint(x);
  u += 0x7fffu + ((u >> 16) & 1u);
  return (unsigned short)(u >> 16);
}
__device__ __forceinline__ float bf2f(unsigned short h){
  return __uint_as_float(((unsigned)h) << 16);
}
__device__ __forceinline__ bf16x8 ld_bf8(const unsigned short* p){
  B8u u; u.s = *reinterpret_cast<const s16x8*>(p); return u.b;
}
__device__ __forceinline__ f32x4 mfma16(bf16x8 a, bf16x8 b, f32x4 c){
  return __builtin_amdgcn_mfma_f32_16x16x32_bf16(a, b, c, 0, 0, 0);
}
__device__ __forceinline__ void gload16(const void* g, void* l){
  __builtin_amdgcn_global_load_lds((const __attribute__((address_space(1))) void*)g,
                                   (__attribute__((address_space(3))) void*)l,
                                   16, 0, 0);
}
__device__ __forceinline__ int cvtpk(float lo, float hi){
  int r;
  asm("v_cvt_pk_bf16_f32 %0, %1, %2" : "=v"(r) : "v"(lo), "v"(hi));
  return r;
}

// ---------------- cast fp32 -> bf16 (flat) ----------------
__global__ __launch_bounds__(256) void cast_bf16_kernel(
    const float* __restrict__ in, unsigned short* __restrict__ out, int n)
{
  int i = (blockIdx.x * 256 + threadIdx.x) * 4;
  if (i < n){
    float4 v = *reinterpret_cast<const float4*>(in + i);
    ushort4 o;
    o.x = f2bf(v.x); o.y = f2bf(v.y); o.z = f2bf(v.z); o.w = f2bf(v.w);
    *reinterpret_cast<ushort4*>(out + i) = o;
  }
}

// ---------------- transpose + cast: in[R][C] fp32 -> out[C][R] bf16 ----------------
__global__ __launch_bounds__(256) void tcast_kernel(
    const float* __restrict__ in, unsigned short* __restrict__ out, int R, int C)
{
  __shared__ float t[32][33];
  int c0 = blockIdx.x * 32, r0 = blockIdx.y * 32;
  int tx = threadIdx.x & 31, ty = threadIdx.x >> 5;
#pragma unroll
  for (int ii = 0; ii < 4; ii++)
    t[ty + ii*8][tx] = in[(size_t)(r0 + ty + ii*8) * C + c0 + tx];
  __syncthreads();
#pragma unroll
  for (int ii = 0; ii < 4; ii++)
    out[(size_t)(c0 + ty + ii*8) * R + r0 + tx] = f2bf(t[tx][ty + ii*8]);
}

// ================= 256x256 8-wave deep-pipelined GEMM (T2+T3+T4+T5) =================
template<int BF16OUT>
__global__ __launch_bounds__(512, 2) void gemm256_kernel(
    const unsigned short* __restrict__ A,
    const unsigned short* __restrict__ BT,
    void* __restrict__ Cv,
    int N, int K, int nbn)
{
  __shared__ unsigned short Ab[2][256 * 64];
  __shared__ unsigned short Bb[2][256 * 64];

  const int tid  = threadIdx.x;
  const int lane = tid & 63;
  const int wid  = tid >> 6;            // 0..7
  const int wm = wid >> 2, wn = wid & 3;
  const int lq = lane & 15, lk = lane >> 4;

  const int cpx = gridDim.x >> 3;
  const int wg  = (blockIdx.x & 7) * cpx + (blockIdx.x >> 3);
  const int bm = wg / nbn, bn = wg % nbn;

  const int l8 = lane >> 3;
  const int sl = ((lane & 7) ^ l8) * 8;
  const unsigned short* agS = A  + (size_t)(bm*256 + wid*16 + l8) * K + sl;
  const unsigned short* bgS = BT + (size_t)(bn*256 + wid*16 + l8) * K + sl;

  f32x4 acc[4][4][2] = {};
  bf16x8 a[4][2], b[2][2];

#define STA(c, h, tt) do {                                                    \
    unsigned short* d = &Ab[c][(h)*8192 + wid*1024];                          \
    const unsigned short* s = agS + (size_t)(h)*128*K + (size_t)(tt)*64;      \
    gload16(s, d); gload16(s + 8*(size_t)K, d + 512);                         \
  } while (0)
#define STB(c, h, tt) do {                                                    \
    unsigned short* d = &Bb[c][(h)*8192 + wid*1024];                          \
    const unsigned short* s = bgS + (size_t)(h)*128*K + (size_t)(tt)*64;      \
    gload16(s, d); gload16(s + 8*(size_t)K, d + 512);                         \
  } while (0)
#define LDA(qa) do {                                                          \
    _Pragma("unroll") for (int m = 0; m < 4; m++)                             \
    _Pragma("unroll") for (int kk = 0; kk < 2; kk++)                          \
      a[m][kk] = ld_bf8(&Ab[cur][((qa)*128 + wm*64 + m*16 + lq)*64            \
                                 + (((kk*4 + lk) ^ (lq & 7)) << 3)]);         \
  } while (0)
#define LDB(qb) do {                                                          \
    _Pragma("unroll") for (int n = 0; n < 2; n++)                             \
    _Pragma("unroll") for (int kk = 0; kk < 2; kk++)                          \
      b[n][kk] = ld_bf8(&Bb[cur][((qb)*128 + wn*32 + n*16 + lq)*64            \
                                 + (((kk*4 + lk) ^ (lq & 7)) << 3)]);         \
  } while (0)
#define MM(qi) do {                                                           \
    __builtin_amdgcn_s_setprio(1);                                            \
    _Pragma("unroll") for (int m = 0; m < 4; m++)                             \
    _Pragma("unroll") for (int n = 0; n < 2; n++)                             \
    _Pragma("unroll") for (int kk = 0; kk < 2; kk++)                          \
      acc[qi][m][n] = mfma16(a[m][kk], b[n][kk], acc[qi][m][n]);              \
    __builtin_amdgcn_s_setprio(0);                                            \
  } while (0)
#define BARR __builtin_amdgcn_s_barrier()
#define VM(n) asm volatile("s_waitcnt vmcnt(" #n ")" ::: "memory")

  STA(0, 0, 0); STB(0, 0, 0); STB(0, 1, 0); STA(0, 1, 0);
  VM(4); BARR;

  const int NT = K >> 6;
  for (int t = 0; t < NT - 1; ++t){
    const int cur = t & 1, nxt = cur ^ 1;
    LDA(0); LDB(0); STA(nxt, 0, t+1);
    BARR; MM(0); VM(4); BARR;
    LDB(1);         STB(nxt, 0, t+1);
    BARR; MM(1); VM(4); BARR;
    LDA(1);         STB(nxt, 1, t+1);
    BARR; MM(2);        BARR;
    LDB(0);         STA(nxt, 1, t+1);
    BARR; MM(3); VM(4); BARR;
  }
  {
    const int cur = (NT - 1) & 1;
    LDA(0); LDB(0); BARR; MM(0); VM(2); BARR;
    LDB(1);         BARR; MM(1); VM(0); BARR;
    LDA(1);         BARR; MM(2);        BARR;
    LDB(0);         BARR; MM(3);        BARR;
  }
#undef STA
#undef STB
#undef LDA
#undef LDB
#undef MM
#undef BARR
#undef VM

#pragma unroll
  for (int qi = 0; qi < 4; qi++){
    const int qa = qi >> 1;
    const int qb = (qi ^ (qi >> 1)) & 1;
    const int r0 = bm*256 + qa*128 + wm*64;
    const int c0 = bn*256 + qb*128 + wn*32;
#pragma unroll
    for (int m = 0; m < 4; m++)
#pragma unroll
      for (int n = 0; n < 2; n++)
#pragma unroll
        for (int i = 0; i < 4; i++){
          const size_t idx = (size_t)(r0 + m*16 + lk*4 + i) * N + (c0 + n*16 + lq);
          if (BF16OUT) ((unsigned short*)Cv)[idx] = f2bf(acc[qi][m][n][i]);
          else         ((float*)Cv)[idx]          = acc[qi][m][n][i];
        }
  }
}

// ---------------- RMSNorm + RoPE + scatter to q/k/vT (qkv bf16) ----------------
__global__ __launch_bounds__(256) void normrope_kernel(
    const unsigned short* __restrict__ qkv,
    const int* __restrict__ positions,
    const float* __restrict__ qw, const float* __restrict__ kw,
    unsigned short* __restrict__ qB,
    unsigned short* __restrict__ kB,
    unsigned short* __restrict__ vT)
{
  const int s = blockIdx.x, b = blockIdx.y;
  const int lane = threadIdx.x & 63, wid = threadIdx.x >> 6;
  const unsigned short* row = qkv + (size_t)(b * S_LEN + s) * NQKV;
  const float fpos = (float)positions[b * S_LEN + s];

#pragma unroll
  for (int t = 0; t < 4; t++){
    const int seg = t * 4 + wid;
    const int base = seg * HD;
    float x0 = bf2f(row[base + lane]);
    float x1 = bf2f(row[base + lane + 64]);
    float x2 = bf2f(row[base + lane + 128]);
    float x3 = bf2f(row[base + lane + 192]);
    if (seg >= 12){
      const int mh = seg - 12;
      unsigned short* vb = vT + (size_t)(b * NKV + mh) * HD * S_LEN + s;
      vb[(size_t)(lane      ) * S_LEN] = f2bf(x0);
      vb[(size_t)(lane +  64) * S_LEN] = f2bf(x1);
      vb[(size_t)(lane + 128) * S_LEN] = f2bf(x2);
      vb[(size_t)(lane + 192) * S_LEN] = f2bf(x3);
    } else {
      const float* w = (seg < 8) ? qw : kw;
      float ssq = x0*x0 + x1*x1 + x2*x2 + x3*x3;
#pragma unroll
      for (int d = 1; d < 64; d <<= 1) ssq += __shfl_xor(ssq, d, 64);
      float rs = rsqrtf(ssq * (1.0f / 256.0f) + 1e-6f);
      float y0 = x0 * rs * (1.0f + w[lane]);
      float y1 = x1 * rs * (1.0f + w[lane + 64]);
      float y2 = x2 * rs * (1.0f + w[lane + 128]);
      float y3 = x3 * rs * (1.0f + w[lane + 192]);
      const float kln = -9.210340371976184f / 128.0f;
      float inv1 = expf((float)lane * kln);
      float inv2 = expf((float)(lane + 64) * kln);
      float s1, c1, s2, c2;
      sincosf(fpos * inv1, &s1, &c1);
      sincosf(fpos * inv2, &s2, &c2);
      float o0 = y0 * c1 - y2 * s1;
      float o2 = y2 * c1 + y0 * s1;
      float o1 = y1 * c2 - y3 * s2;
      float o3 = y3 * c2 + y1 * s2;
      unsigned short* dst = (seg < 8)
        ? qB + ((size_t)(b * NH  +  seg     ) * S_LEN + s) * HD
        : kB + ((size_t)(b * NKV + (seg - 8)) * S_LEN + s) * HD;
      dst[lane      ] = f2bf(o0);
      dst[lane +  64] = f2bf(o1);
      dst[lane + 128] = f2bf(o2);
      dst[lane + 192] = f2bf(o3);
    }
  }
}

// ---------------- mask bit pack + work-queue counter reset ----------------
__global__ void maskbits_kernel(const int* __restrict__ amask, unsigned* __restrict__ bm,
                                int* __restrict__ ctr)
{
  int t = threadIdx.x;                 // 0..127
  int b = t >> 6, tile = t & 63;
  unsigned m = 0;
  for (int j = 0; j < 32; j++)
    m |= (amask[b * S_LEN + tile * 32 + j] != 0 ? 1u : 0u) << j;
  bm[t] = m;
  if (t < 8) ctr[t] = 0;
}

// ---------------- flash attention v8: K in LDS, V from L2, 2 blocks/CU ----------------
// Grid 512 (2 blocks/CU -> 8 waves/CU). combo c = blockIdx.x & 7 (id%8 -> XCD,
// R5-confirmed) fixes (mh,b); per-combo atomic queue of 64 q-tile items with a
// balanced idx->qt map (heavy/light alternate) so co-resident blocks get ~equal work.
// V is NOT staged: per-XCD K+V = 2MB (L2-resident) -> PV reads vT from L2 directly,
// moving that traffic off the DS pipe onto the idle VMEM pipe.
__global__ __launch_bounds__(256) void attn_kernel(
    const unsigned short* __restrict__ qB,
    const unsigned short* __restrict__ kB,
    const unsigned short* __restrict__ vT,
    const unsigned* __restrict__ bmG,
    unsigned short* __restrict__ attnO,
    int* __restrict__ ctr)
{
  __shared__ unsigned short Kb[2][32 * 256];    // [key][d-granule ^ (key&7)], 16KB/buf
  __shared__ unsigned bm_lds[64];
  __shared__ int s_idx;

  const int tid  = threadIdx.x;
  const int lane = tid & 63, wid = tid >> 6;
  const int c  = blockIdx.x & 7;
  const int mh = c & 3, b = c >> 2;
  const int h  = mh * 2 + (wid >> 1);
  const int lq = lane & 15, lk = lane >> 4;

  if (tid < 64) bm_lds[tid] = bmG[(b << 6) + tid];

  const unsigned short* kbase = kB + (size_t)(b * NKV + mh) * S_LEN * HD;
  const unsigned short* vbase = vT + (size_t)(b * NKV + mh) * HD * S_LEN;
  const int krow0 = wid * 2 + (lane >> 5);
  const int kgsrc = (lane & 31) ^ (krow0 & 7);
  const unsigned short* kg0 = kbase + (size_t)krow0 * HD + kgsrc * 8;
  // V read base: d-row = db*16 + lq, key = kt + lk*8 (R1-verified layout)
  const unsigned short* vg = vbase + (size_t)lq * S_LEN + lk * 8;

#define STAGE_K(buf, ktv)                                                      \
  do {                                                                         \
    _Pragma("unroll")                                                          \
    for (int r = 0; r < 4; r++)                                                \
      gload16(kg0 + (size_t)(ktv) * HD + r * (8 * HD),                         \
              &Kb[buf][wid * 512 + r * 2048]);                                 \
  } while (0)

  for (;;){
    if (tid == 0) s_idx = atomicAdd(&ctr[c], 1);
    __syncthreads();
    const int idx = s_idx;
    __syncthreads();
    if (idx >= 64) break;
    // balanced heavy/light alternation: 63,0,62,1,61,2,...
    const int qt = (idx & 1) ? (idx >> 1) : (63 - (idx >> 1));

    const int q0 = qt * 32 + (wid & 1) * 16;
    const int q  = q0 + lq;

    const unsigned short* qbase = qB + ((size_t)(b * NH + h) * S_LEN + q0 + lq) * HD + lk * 8;
    bf16x8 aq[8];
#pragma unroll
    for (int ks = 0; ks < 8; ks++) aq[ks] = ld_bf8(qbase + ks * 32);
    asm volatile("s_waitcnt vmcnt(0)" ::: "memory");

    float mi = -__builtin_inff(), li = 0.f;
    f32x4 oacc[16] = {};

    const int ktmax = qt * 32;

    STAGE_K(0, 0);
    if (ktmax >= 32) STAGE_K(1, 32);

    int cur = 0;
    for (int kt = 0; kt <= ktmax; kt += 32, cur ^= 1){
      if (kt < ktmax) asm volatile("s_waitcnt vmcnt(4)" ::: "memory");
      else            asm volatile("s_waitcnt vmcnt(0)" ::: "memory");
      __syncthreads();                                   // (A) Kb[cur] published

      f32x4 s0 = {0.f,0.f,0.f,0.f}, s1 = {0.f,0.f,0.f,0.f};
#pragma unroll
      for (int ks = 0; ks < 8; ks++){
        const int slot = (((ks * 4 + lk) ^ (lq & 7)) << 3);
        bf16x8 kf0 = ld_bf8(&Kb[cur][lq * 256 + slot]);
        bf16x8 kf1 = ld_bf8(&Kb[cur][(16 + lq) * 256 + slot]);
        s0 = mfma16(kf0, aq[ks], s0);
        s1 = mfma16(kf1, aq[ks], s1);
      }

      const unsigned mask32 = bm_lds[kt >> 5];
      const int koff = lk * 4;
      float v0[4], v1[4];
#pragma unroll
      for (int j2 = 0; j2 < 4; j2++){
        const bool cc0 = (kt + koff + j2 <= q)      && ((mask32 >> (koff + j2)) & 1u);
        const bool cc1 = (kt + 16 + koff + j2 <= q) && ((mask32 >> (16 + koff + j2)) & 1u);
        v0[j2] = cc0 ? s0[j2] * SCALE_ATT : -__builtin_inff();
        v1[j2] = cc1 ? s1[j2] * SCALE_ATT : -__builtin_inff();
      }
      float tm = fmaxf(fmaxf(fmaxf(v0[0], v0[1]), fmaxf(v0[2], v0[3])),
                       fmaxf(fmaxf(v1[0], v1[1]), fmaxf(v1[2], v1[3])));
      tm = fmaxf(tm, __shfl_xor(tm, 16, 64));
      tm = fmaxf(tm, __shfl_xor(tm, 32, 64));

      float p0[4], p1[4];
      if (__all(tm <= mi + 8.0f)){
        const float mns = fmaxf(mi, -1e30f);
#pragma unroll
        for (int j2 = 0; j2 < 4; j2++){
          p0[j2] = __expf(v0[j2] - mns);
          p1[j2] = __expf(v1[j2] - mns);
        }
        float rs = (p0[0] + p0[1]) + (p0[2] + p0[3]) + (p1[0] + p1[1]) + (p1[2] + p1[3]);
        rs += __shfl_xor(rs, 16, 64);
        rs += __shfl_xor(rs, 32, 64);
        li += rs;
      } else {
        const float mn  = fmaxf(mi, tm);
        const float mns = fmaxf(mn, -1e30f);
#pragma unroll
        for (int j2 = 0; j2 < 4; j2++){
          p0[j2] = __expf(v0[j2] - mns);
          p1[j2] = __expf(v1[j2] - mns);
        }
        const float a_ = __expf(mi - mns);
        float rs = (p0[0] + p0[1]) + (p0[2] + p0[3]) + (p1[0] + p1[1]) + (p1[2] + p1[3]);
        rs += __shfl_xor(rs, 16, 64);
        rs += __shfl_xor(rs, 32, 64);
        li = li * a_ + rs;
        mi = mn;
        float av[4];
#pragma unroll
        for (int i = 0; i < 4; i++)
          av[i] = __shfl(a_, (lane & 48) | (lk * 4 + i), 64);
#pragma unroll
        for (int db = 0; db < 16; db++){
          f32x4 o = oacc[db];
#pragma unroll
          for (int i = 0; i < 4; i++) o[i] *= av[i];
          oacc[db] = o;
        }
      }

      const int w0 = cvtpk(p0[0], p0[1]), w1 = cvtpk(p0[2], p0[3]);
      const int w2 = cvtpk(p1[0], p1[1]), w3 = cvtpk(p1[2], p1[3]);
      const int sA = (((lk & 1) * 2) << 4) | lq;
      const int sB = sA + 16;
      const int a0 = __shfl(w0, sA, 64), a1 = __shfl(w1, sA, 64);
      const int b0 = __shfl(w0, sB, 64), b1 = __shfl(w1, sB, 64);
      const int c0w = __shfl(w2, sA, 64), c1w = __shfl(w3, sA, 64);
      const int d0w = __shfl(w2, sB, 64), d1w = __shfl(w3, sB, 64);
      const bool hi = (lk >= 2);
      I4B8 pau;
      pau.i.x = hi ? c0w : a0;
      pau.i.y = hi ? c1w : a1;
      pau.i.z = hi ? d0w : b0;
      pau.i.w = hi ? d1w : b1;

      // ---- PV: V read directly from L2 (vT global), keys kt..kt+31 ----
      const unsigned short* vp = vg + kt;
#pragma unroll
      for (int db = 0; db < 16; db++){
        bf16x8 vf = ld_bf8(vp + (size_t)db * 16 * S_LEN);
        oacc[db] = mfma16(pau.b, vf, oacc[db]);
      }

      __syncthreads();                                   // (B) all waves done with Kb[cur]
      if (kt + 64 <= ktmax) STAGE_K(cur, kt + 64);
    }

#pragma unroll
    for (int i = 0; i < 4; i++){
      const float lf = __shfl(li, (lane & 48) | (lk * 4 + i), 64);
      const float inv = 1.0f / lf;
      unsigned short* orow = attnO + (size_t)(b * S_LEN + q0 + lk*4 + i) * QSZ + h * HD + lq;
#pragma unroll
      for (int db = 0; db < 16; db++)
        orow[db * 16] = f2bf(oacc[db][i] * inv);
    }
  }
#undef STAGE_K
}

extern "C" void kernel_launch(void* const* d_in, const int* in_sizes, int n_in,
                              void* d_out, int out_size, void* d_ws, size_t ws_size,
                              hipStream_t stream)
{
  const int*   positions = (const int*)  d_in[0];
  const float* hidden    = (const float*)d_in[1];
  const int*   amask     = (const int*)  d_in[2];
  const float* Wqkv      = (const float*)d_in[3];
  const float* Wo        = (const float*)d_in[4];
  const float* qw        = (const float*)d_in[5];
  const float* kw        = (const float*)d_in[6];
  float* out = (float*)d_out;

  char* ws = (char*)d_ws;
  unsigned short* hB    = (unsigned short*)(ws);               // 4096x2560 bf16
  unsigned short* attnO = (unsigned short*)(ws);               // alias (4096x2048 bf16)
  unsigned short* WqT   = (unsigned short*)(ws + 20971520);    // [4096][2560] bf16
  unsigned short* WoT   = (unsigned short*)(ws + 41943040);    // [2560][2048] bf16
  unsigned short* qkvB  = (unsigned short*)(ws + 52428800);    // [4096][4096] bf16
  unsigned short* qb    = (unsigned short*)(ws + 119537664);   // [B][NH][S][HD]
  unsigned short* kb    = (unsigned short*)(ws + 136314880);   // [B][NKV][S][HD]
  unsigned short* vt    = (unsigned short*)(ws + 144703488);   // [B][NKV][HD][S]
  unsigned*       bm    = (unsigned*)     (ws + 153092096);   // [B][64] mask bits
  int*            ctr   = (int*)          (ws + 153092608);   // [8] work-queue counters

  cast_bf16_kernel<<<dim3(MROWS * HIDDEN / 1024), 256, 0, stream>>>(hidden, hB, MROWS * HIDDEN);
  tcast_kernel<<<dim3(NQKV / 32, HIDDEN / 32), 256, 0, stream>>>(Wqkv, WqT, HIDDEN, NQKV);
  tcast_kernel<<<dim3(HIDDEN / 32, QSZ / 32), 256, 0, stream>>>(Wo, WoT, QSZ, HIDDEN);
  maskbits_kernel<<<dim3(1), 128, 0, stream>>>(amask, bm, ctr);

  // GEMM1: [4096 x 2560] * [2560 x 4096] -> qkvB (bf16); grid 256 blocks
  gemm256_kernel<1><<<dim3((MROWS/256) * (NQKV/256)), 512, 0, stream>>>(
      hB, WqT, qkvB, NQKV, HIDDEN, NQKV/256);

  normrope_kernel<<<dim3(S_LEN, BATCH), 256, 0, stream>>>(qkvB, positions, qw, kw, qb, kb, vt);

  attn_kernel<<<dim3(512), 256, 0, stream>>>(qb, kb, vt, bm, attnO, ctr);

  // GEMM2: [4096 x 2048] * [2048 x 2560] -> out (f32); grid 160 blocks
  gemm256_kernel<0><<<dim3((MROWS/256) * (HIDDEN/256)), 512, 0, stream>>>(
      attnO, WoT, out, HIDDEN, QSZ, HIDDEN/256);
}

// Round 10
// 362.264 us; speedup vs baseline: 1.3060x; 1.3060x over previous
//
#include <hip/hip_runtime.h>
#include <stdint.h>

#define S_LEN 2048
#define BATCH 2
#define HIDDEN 2560
#define NH 8
#define NKV 4
#define HD 256
#define QSZ (NH*HD)          // 2048
#define NQKV 4096            // QSZ + 2*KVSZ
#define MROWS (BATCH*S_LEN)  // 4096
#define SCALE_ATT 0.0625f

using bf16x8 = __attribute__((__ext_vector_type__(8))) __bf16;
using f32x4  = __attribute__((__ext_vector_type__(4))) float;
using s16x8  = __attribute__((__ext_vector_type__(8))) short;

union B8u { s16x8 s; bf16x8 b; };
union I4B8 { int4 i; bf16x8 b; };

__device__ __forceinline__ unsigned short f2bf(float x){
  unsigned u = __float_as_uint(x);
  u += 0x7fffu + ((u >> 16) & 1u);
  return (unsigned short)(u >> 16);
}
__device__ __forceinline__ float bf2f(unsigned short h){
  return __uint_as_float(((unsigned)h) << 16);
}
__device__ __forceinline__ bf16x8 ld_bf8(const unsigned short* p){
  B8u u; u.s = *reinterpret_cast<const s16x8*>(p); return u.b;
}
__device__ __forceinline__ f32x4 mfma16(bf16x8 a, bf16x8 b, f32x4 c){
  return __builtin_amdgcn_mfma_f32_16x16x32_bf16(a, b, c, 0, 0, 0);
}
__device__ __forceinline__ void gload16(const void* g, void* l){
  __builtin_amdgcn_global_load_lds((const __attribute__((address_space(1))) void*)g,
                                   (__attribute__((address_space(3))) void*)l,
                                   16, 0, 0);
}
__device__ __forceinline__ int cvtpk(float lo, float hi){
  int r;
  asm("v_cvt_pk_bf16_f32 %0, %1, %2" : "=v"(r) : "v"(lo), "v"(hi));
  return r;
}

// ---------------- cast fp32 -> bf16 (flat) ----------------
__global__ __launch_bounds__(256) void cast_bf16_kernel(
    const float* __restrict__ in, unsigned short* __restrict__ out, int n)
{
  int i = (blockIdx.x * 256 + threadIdx.x) * 4;
  if (i < n){
    float4 v = *reinterpret_cast<const float4*>(in + i);
    ushort4 o;
    o.x = f2bf(v.x); o.y = f2bf(v.y); o.z = f2bf(v.z); o.w = f2bf(v.w);
    *reinterpret_cast<ushort4*>(out + i) = o;
  }
}

// ---------------- transpose + cast: in[R][C] fp32 -> out[C][R] bf16 ----------------
__global__ __launch_bounds__(256) void tcast_kernel(
    const float* __restrict__ in, unsigned short* __restrict__ out, int R, int C)
{
  __shared__ float t[32][33];
  int c0 = blockIdx.x * 32, r0 = blockIdx.y * 32;
  int tx = threadIdx.x & 31, ty = threadIdx.x >> 5;
#pragma unroll
  for (int ii = 0; ii < 4; ii++)
    t[ty + ii*8][tx] = in[(size_t)(r0 + ty + ii*8) * C + c0 + tx];
  __syncthreads();
#pragma unroll
  for (int ii = 0; ii < 4; ii++)
    out[(size_t)(c0 + ty + ii*8) * R + r0 + tx] = f2bf(t[tx][ty + ii*8]);
}

// ================= 256x256 8-wave deep-pipelined GEMM (T2+T3+T4+T5) =================
template<int BF16OUT>
__global__ __launch_bounds__(512, 2) void gemm256_kernel(
    const unsigned short* __restrict__ A,
    const unsigned short* __restrict__ BT,
    void* __restrict__ Cv,
    int N, int K, int nbn)
{
  __shared__ unsigned short Ab[2][256 * 64];
  __shared__ unsigned short Bb[2][256 * 64];

  const int tid  = threadIdx.x;
  const int lane = tid & 63;
  const int wid  = tid >> 6;            // 0..7
  const int wm = wid >> 2, wn = wid & 3;
  const int lq = lane & 15, lk = lane >> 4;

  const int cpx = gridDim.x >> 3;
  const int wg  = (blockIdx.x & 7) * cpx + (blockIdx.x >> 3);
  const int bm = wg / nbn, bn = wg % nbn;

  const int l8 = lane >> 3;
  const int sl = ((lane & 7) ^ l8) * 8;
  const unsigned short* agS = A  + (size_t)(bm*256 + wid*16 + l8) * K + sl;
  const unsigned short* bgS = BT + (size_t)(bn*256 + wid*16 + l8) * K + sl;

  f32x4 acc[4][4][2] = {};
  bf16x8 a[4][2], b[2][2];

#define STA(c, h, tt) do {                                                    \
    unsigned short* d = &Ab[c][(h)*8192 + wid*1024];                          \
    const unsigned short* s = agS + (size_t)(h)*128*K + (size_t)(tt)*64;      \
    gload16(s, d); gload16(s + 8*(size_t)K, d + 512);                         \
  } while (0)
#define STB(c, h, tt) do {                                                    \
    unsigned short* d = &Bb[c][(h)*8192 + wid*1024];                          \
    const unsigned short* s = bgS + (size_t)(h)*128*K + (size_t)(tt)*64;      \
    gload16(s, d); gload16(s + 8*(size_t)K, d + 512);                         \
  } while (0)
#define LDA(qa) do {                                                          \
    _Pragma("unroll") for (int m = 0; m < 4; m++)                             \
    _Pragma("unroll") for (int kk = 0; kk < 2; kk++)                          \
      a[m][kk] = ld_bf8(&Ab[cur][((qa)*128 + wm*64 + m*16 + lq)*64            \
                                 + (((kk*4 + lk) ^ (lq & 7)) << 3)]);         \
  } while (0)
#define LDB(qb) do {                                                          \
    _Pragma("unroll") for (int n = 0; n < 2; n++)                             \
    _Pragma("unroll") for (int kk = 0; kk < 2; kk++)                          \
      b[n][kk] = ld_bf8(&Bb[cur][((qb)*128 + wn*32 + n*16 + lq)*64            \
                                 + (((kk*4 + lk) ^ (lq & 7)) << 3)]);         \
  } while (0)
#define MM(qi) do {                                                           \
    __builtin_amdgcn_s_setprio(1);                                            \
    _Pragma("unroll") for (int m = 0; m < 4; m++)                             \
    _Pragma("unroll") for (int n = 0; n < 2; n++)                             \
    _Pragma("unroll") for (int kk = 0; kk < 2; kk++)                          \
      acc[qi][m][n] = mfma16(a[m][kk], b[n][kk], acc[qi][m][n]);              \
    __builtin_amdgcn_s_setprio(0);                                            \
  } while (0)
#define BARR __builtin_amdgcn_s_barrier()
#define VM(n) asm volatile("s_waitcnt vmcnt(" #n ")" ::: "memory")

  STA(0, 0, 0); STB(0, 0, 0); STB(0, 1, 0); STA(0, 1, 0);
  VM(4); BARR;

  const int NT = K >> 6;
  for (int t = 0; t < NT - 1; ++t){
    const int cur = t & 1, nxt = cur ^ 1;
    LDA(0); LDB(0); STA(nxt, 0, t+1);
    BARR; MM(0); VM(4); BARR;
    LDB(1);         STB(nxt, 0, t+1);
    BARR; MM(1); VM(4); BARR;
    LDA(1);         STB(nxt, 1, t+1);
    BARR; MM(2);        BARR;
    LDB(0);         STA(nxt, 1, t+1);
    BARR; MM(3); VM(4); BARR;
  }
  {
    const int cur = (NT - 1) & 1;
    LDA(0); LDB(0); BARR; MM(0); VM(2); BARR;
    LDB(1);         BARR; MM(1); VM(0); BARR;
    LDA(1);         BARR; MM(2);        BARR;
    LDB(0);         BARR; MM(3);        BARR;
  }
#undef STA
#undef STB
#undef LDA
#undef LDB
#undef MM
#undef BARR
#undef VM

#pragma unroll
  for (int qi = 0; qi < 4; qi++){
    const int qa = qi >> 1;
    const int qb = (qi ^ (qi >> 1)) & 1;
    const int r0 = bm*256 + qa*128 + wm*64;
    const int c0 = bn*256 + qb*128 + wn*32;
#pragma unroll
    for (int m = 0; m < 4; m++)
#pragma unroll
      for (int n = 0; n < 2; n++)
#pragma unroll
        for (int i = 0; i < 4; i++){
          const size_t idx = (size_t)(r0 + m*16 + lk*4 + i) * N + (c0 + n*16 + lq);
          if (BF16OUT) ((unsigned short*)Cv)[idx] = f2bf(acc[qi][m][n][i]);
          else         ((float*)Cv)[idx]          = acc[qi][m][n][i];
        }
  }
}

// ---------------- RMSNorm + RoPE + scatter to q/k/vT (qkv bf16) ----------------
__global__ __launch_bounds__(256) void normrope_kernel(
    const unsigned short* __restrict__ qkv,
    const int* __restrict__ positions,
    const float* __restrict__ qw, const float* __restrict__ kw,
    unsigned short* __restrict__ qB,
    unsigned short* __restrict__ kB,
    unsigned short* __restrict__ vT)
{
  const int s = blockIdx.x, b = blockIdx.y;
  const int lane = threadIdx.x & 63, wid = threadIdx.x >> 6;
  const unsigned short* row = qkv + (size_t)(b * S_LEN + s) * NQKV;
  const float fpos = (float)positions[b * S_LEN + s];

#pragma unroll
  for (int t = 0; t < 4; t++){
    const int seg = t * 4 + wid;
    const int base = seg * HD;
    float x0 = bf2f(row[base + lane]);
    float x1 = bf2f(row[base + lane + 64]);
    float x2 = bf2f(row[base + lane + 128]);
    float x3 = bf2f(row[base + lane + 192]);
    if (seg >= 12){
      const int mh = seg - 12;
      unsigned short* vb = vT + (size_t)(b * NKV + mh) * HD * S_LEN + s;
      vb[(size_t)(lane      ) * S_LEN] = f2bf(x0);
      vb[(size_t)(lane +  64) * S_LEN] = f2bf(x1);
      vb[(size_t)(lane + 128) * S_LEN] = f2bf(x2);
      vb[(size_t)(lane + 192) * S_LEN] = f2bf(x3);
    } else {
      const float* w = (seg < 8) ? qw : kw;
      float ssq = x0*x0 + x1*x1 + x2*x2 + x3*x3;
#pragma unroll
      for (int d = 1; d < 64; d <<= 1) ssq += __shfl_xor(ssq, d, 64);
      float rs = rsqrtf(ssq * (1.0f / 256.0f) + 1e-6f);
      float y0 = x0 * rs * (1.0f + w[lane]);
      float y1 = x1 * rs * (1.0f + w[lane + 64]);
      float y2 = x2 * rs * (1.0f + w[lane + 128]);
      float y3 = x3 * rs * (1.0f + w[lane + 192]);
      const float kln = -9.210340371976184f / 128.0f;
      float inv1 = expf((float)lane * kln);
      float inv2 = expf((float)(lane + 64) * kln);
      float s1, c1, s2, c2;
      sincosf(fpos * inv1, &s1, &c1);
      sincosf(fpos * inv2, &s2, &c2);
      float o0 = y0 * c1 - y2 * s1;
      float o2 = y2 * c1 + y0 * s1;
      float o1 = y1 * c2 - y3 * s2;
      float o3 = y3 * c2 + y1 * s2;
      unsigned short* dst = (seg < 8)
        ? qB + ((size_t)(b * NH  +  seg     ) * S_LEN + s) * HD
        : kB + ((size_t)(b * NKV + (seg - 8)) * S_LEN + s) * HD;
      dst[lane      ] = f2bf(o0);
      dst[lane +  64] = f2bf(o1);
      dst[lane + 128] = f2bf(o2);
      dst[lane + 192] = f2bf(o3);
    }
  }
}

// ---------------- mask bit pack + work-queue counter reset ----------------
__global__ void maskbits_kernel(const int* __restrict__ amask, unsigned* __restrict__ bm,
                                int* __restrict__ ctr)
{
  int t = threadIdx.x;                 // 0..127
  int b = t >> 6, tile = t & 63;
  unsigned m = 0;
  for (int j = 0; j < 32; j++)
    m |= (amask[b * S_LEN + tile * 32 + j] != 0 ? 1u : 0u) << j;
  bm[t] = m;
  if (t < 8) ctr[t] = 0;
}

// ---------------- flash attention v9: kv-split waves, 16-row items, 2 blocks/CU ----------------
// Grid 512 (2 blocks/CU -> 8 waves/CU = 2/SIMD). combo c = blockIdx.x & 7 -> (mh,b),
// 64 workers/combo; 128 items/combo of 16 q-rows, heavy-first queue.
// Block = 4 waves: (hh = wid>>1 -> head, sp = wid&1 -> key-parity split).
// Wave (hh,sp): 16 q-rows x key-tiles t=2*it+sp (32 keys each). K,V single-buffered
// per sp with a counted depth-1 pipeline: stage K(it+1) after QK-consume barrier,
// V(it+1) after PV-consume barrier; steady-state waits vmcnt(8). sp-pair merges
// (m,l,O) once per item via LDS (obuf aliases Ks after final drain).
__global__ __launch_bounds__(256) void attn_kernel(
    const unsigned short* __restrict__ qB,
    const unsigned short* __restrict__ kB,
    const unsigned short* __restrict__ vT,
    const unsigned* __restrict__ bmG,
    unsigned short* __restrict__ attnO,
    int* __restrict__ ctr)
{
  __shared__ unsigned short Ks[2][32 * 256];   // [sp][key][d-granule ^ (key&7)], 16KB each
  __shared__ unsigned short Vs[2][256 * 32];   // [sp][d][key-chunk swz], 16KB each
  __shared__ unsigned bm_lds[64];
  __shared__ float mlbuf[2][2][16];            // [hh][m/l][row]
  __shared__ int s_idx;

  const int tid  = threadIdx.x;
  const int lane = tid & 63, wid = tid >> 6;
  const int c  = blockIdx.x & 7;
  const int mh = c & 3, b = c >> 2;
  const int hh = wid >> 1, sp = wid & 1;
  const int h  = mh * 2 + hh;
  const int lq = lane & 15, lk = lane >> 4;

  if (tid < 64) bm_lds[tid] = bmG[(b << 6) + tid];

  const unsigned short* kbase = kB + (size_t)(b * NKV + mh) * S_LEN * HD;
  const unsigned short* vbase = vT + (size_t)(b * NKV + mh) * HD * S_LEN;
  // K staging: 4 waves cooperatively fill ONE 32-key tile with 4 gloads/wave
  const int krow0 = wid * 2 + (lane >> 5);
  const int kgsrc = (lane & 31) ^ (krow0 & 7);
  const unsigned short* kg0 = kbase + (size_t)krow0 * HD + kgsrc * 8;
  // V staging: 4 waves fill one 256d x 32key tile with 4 gloads/wave
  const int vd0 = wid * 16 + (lane >> 2);
  const int vgsrc = (lane & 3) ^ ((lane >> 3) & 3);
  const unsigned short* vg0 = vbase + (size_t)vd0 * S_LEN + vgsrc * 8;

  float* obuf = (float*)&Ks[0][0];             // merge buffer aliases Ks (32KB)

#define STAGE_K2(it1)                                                          \
  do {                                                                         \
    const int ka = min((it1) * 64,      S_LEN - 32);                           \
    const int kb2 = min((it1) * 64 + 32, S_LEN - 32);                          \
    _Pragma("unroll")                                                          \
    for (int r = 0; r < 4; r++)                                                \
      gload16(kg0 + (size_t)ka * HD + r * (8 * HD),                            \
              &Ks[0][wid * 512 + r * 2048]);                                   \
    _Pragma("unroll")                                                          \
    for (int r = 0; r < 4; r++)                                                \
      gload16(kg0 + (size_t)kb2 * HD + r * (8 * HD),                           \
              &Ks[1][wid * 512 + r * 2048]);                                   \
  } while (0)
#define STAGE_V2(it1)                                                          \
  do {                                                                         \
    const int ka = min((it1) * 64,      S_LEN - 32);                           \
    const int kb2 = min((it1) * 64 + 32, S_LEN - 32);                          \
    _Pragma("unroll")                                                          \
    for (int r = 0; r < 4; r++)                                                \
      gload16(vg0 + ka  + (size_t)r * (64 * S_LEN),                            \
              &Vs[0][wid * 512 + r * 2048]);                                   \
    _Pragma("unroll")                                                          \
    for (int r = 0; r < 4; r++)                                                \
      gload16(vg0 + kb2 + (size_t)r * (64 * S_LEN),                            \
              &Vs[1][wid * 512 + r * 2048]);                                   \
  } while (0)

  for (;;){
    if (tid == 0) s_idx = atomicAdd(&ctr[c], 1);
    __syncthreads();
    const int idx = s_idx;
    __syncthreads();
    if (idx >= 128) break;
    const int qt16 = 127 - idx;                 // heavy-first
    const int q0 = qt16 * 16;
    const int q  = q0 + lq;
    const int nt = (qt16 >> 1) + 1;             // # 32-key tiles needed
    const int L  = (nt + 1) >> 1;               // iterations (64 keys each)

    // ---- Q fragments ----
    const unsigned short* qbase = qB + ((size_t)(b * NH + h) * S_LEN + q0 + lq) * HD + lk * 8;
    bf16x8 aq[8];
#pragma unroll
    for (int ks = 0; ks < 8; ks++) aq[ks] = ld_bf8(qbase + ks * 32);
    asm volatile("s_waitcnt vmcnt(0)" ::: "memory");

    float mi = -__builtin_inff(), li = 0.f;
    f32x4 oacc[16] = {};

    STAGE_K2(0);                                // 8 gloads/wave
    STAGE_V2(0);                                // 8 gloads/wave

    for (int it = 0; it < L; ++it){
      const bool more = (it + 1 < L);
      const int kt = it * 64 + sp * 32;         // this wave's key tile

      asm volatile("s_waitcnt vmcnt(8)" ::: "memory");   // K(it) landed (V flying)
      __syncthreads();                                   // (A) Ks published

      // ---- swapped QK^T from Ks[sp] ----
      f32x4 s0 = {0.f,0.f,0.f,0.f}, s1 = {0.f,0.f,0.f,0.f};
#pragma unroll
      for (int ks = 0; ks < 8; ks++){
        const int slot = (((ks * 4 + lk) ^ (lq & 7)) << 3);
        bf16x8 kf0 = ld_bf8(&Ks[sp][lq * 256 + slot]);
        bf16x8 kf1 = ld_bf8(&Ks[sp][(16 + lq) * 256 + slot]);
        s0 = mfma16(kf0, aq[ks], s0);
        s1 = mfma16(kf1, aq[ks], s1);
      }

      __syncthreads();                                   // (C) all done reading Ks
      if (more) STAGE_K2(it + 1);                        // overwrite Ks, overlap softmax+PV

      // ---- in-register online softmax with defer-max ----
      const unsigned mask32 = bm_lds[(kt >> 5) & 63];
      const int koff = lk * 4;
      float v0[4], v1[4];
#pragma unroll
      for (int j2 = 0; j2 < 4; j2++){
        const bool cc0 = (kt + koff + j2 <= q)      && ((mask32 >> (koff + j2)) & 1u);
        const bool cc1 = (kt + 16 + koff + j2 <= q) && ((mask32 >> (16 + koff + j2)) & 1u);
        v0[j2] = cc0 ? s0[j2] * SCALE_ATT : -__builtin_inff();
        v1[j2] = cc1 ? s1[j2] * SCALE_ATT : -__builtin_inff();
      }
      float tm = fmaxf(fmaxf(fmaxf(v0[0], v0[1]), fmaxf(v0[2], v0[3])),
                       fmaxf(fmaxf(v1[0], v1[1]), fmaxf(v1[2], v1[3])));
      tm = fmaxf(tm, __shfl_xor(tm, 16, 64));
      tm = fmaxf(tm, __shfl_xor(tm, 32, 64));

      float p0[4], p1[4];
      if (__all(tm <= mi + 8.0f)){
        const float mns = fmaxf(mi, -1e30f);
#pragma unroll
        for (int j2 = 0; j2 < 4; j2++){
          p0[j2] = __expf(v0[j2] - mns);
          p1[j2] = __expf(v1[j2] - mns);
        }
        float rs = (p0[0] + p0[1]) + (p0[2] + p0[3]) + (p1[0] + p1[1]) + (p1[2] + p1[3]);
        rs += __shfl_xor(rs, 16, 64);
        rs += __shfl_xor(rs, 32, 64);
        li += rs;
      } else {
        const float mn  = fmaxf(mi, tm);
        const float mns = fmaxf(mn, -1e30f);
#pragma unroll
        for (int j2 = 0; j2 < 4; j2++){
          p0[j2] = __expf(v0[j2] - mns);
          p1[j2] = __expf(v1[j2] - mns);
        }
        const float a_ = __expf(mi - mns);
        float rs = (p0[0] + p0[1]) + (p0[2] + p0[3]) + (p1[0] + p1[1]) + (p1[2] + p1[3]);
        rs += __shfl_xor(rs, 16, 64);
        rs += __shfl_xor(rs, 32, 64);
        li = li * a_ + rs;
        mi = mn;
        float av[4];
#pragma unroll
        for (int i = 0; i < 4; i++)
          av[i] = __shfl(a_, (lane & 48) | (lk * 4 + i), 64);
#pragma unroll
        for (int db = 0; db < 16; db++){
          f32x4 o = oacc[db];
#pragma unroll
          for (int i = 0; i < 4; i++) o[i] *= av[i];
          oacc[db] = o;
        }
      }

      // ---- redistribute P -> PV A-fragment ----
      const int w0 = cvtpk(p0[0], p0[1]), w1 = cvtpk(p0[2], p0[3]);
      const int w2 = cvtpk(p1[0], p1[1]), w3 = cvtpk(p1[2], p1[3]);
      const int sA = (((lk & 1) * 2) << 4) | lq;
      const int sB = sA + 16;
      const int a0 = __shfl(w0, sA, 64), a1 = __shfl(w1, sA, 64);
      const int b0 = __shfl(w0, sB, 64), b1 = __shfl(w1, sB, 64);
      const int c0w = __shfl(w2, sA, 64), c1w = __shfl(w3, sA, 64);
      const int d0w = __shfl(w2, sB, 64), d1w = __shfl(w3, sB, 64);
      const bool hi = (lk >= 2);
      I4B8 pau;
      pau.i.x = hi ? c0w : a0;
      pau.i.y = hi ? c1w : a1;
      pau.i.z = hi ? d0w : b0;
      pau.i.w = hi ? d1w : b1;

      // ---- V(it) ready ----
      if (more) asm volatile("s_waitcnt vmcnt(8)" ::: "memory");  // V done, K(it+1) flying
      else      asm volatile("s_waitcnt vmcnt(0)" ::: "memory");
      __syncthreads();                                   // (D) Vs published

      const int vslot = (lk ^ ((lq >> 1) & 3)) << 3;
#pragma unroll
      for (int db = 0; db < 16; db++){
        bf16x8 vf = ld_bf8(&Vs[sp][(db * 16 + lq) * 32 + vslot]);
        oacc[db] = mfma16(pau.b, vf, oacc[db]);
      }

      __syncthreads();                                   // (B) all done reading Vs
      if (more) STAGE_V2(it + 1);
    }

    // ---- sp-pair merge (no loads outstanding; obuf aliases Ks) ----
    if (sp){
      if (lk == 0){
        mlbuf[hh][0][lq] = mi;
        mlbuf[hh][1][lq] = li;
      }
#pragma unroll
      for (int db = 0; db < 16; db++)
#pragma unroll
        for (int i = 0; i < 4; i++)
          obuf[hh * 4096 + (lk*4 + i) * 256 + db*16 + lq] = oacc[db][i];
    }
    __syncthreads();
    if (!sp){
      const float m1 = mlbuf[hh][0][lq];
      const float l1 = mlbuf[hh][1][lq];
      const float ms  = fmaxf(mi, m1);
      const float msf = fmaxf(ms, -1e30f);
      const float a0f = __expf(mi - msf);
      const float a1f = __expf(m1 - msf);
      const float inv = 1.0f / (li * a0f + l1 * a1f);
      const float s0f = a0f * inv, s1f = a1f * inv;
      float sc0[4], sc1[4];
#pragma unroll
      for (int i = 0; i < 4; i++){
        sc0[i] = __shfl(s0f, (lane & 48) | (lk*4 + i), 64);
        sc1[i] = __shfl(s1f, (lane & 48) | (lk*4 + i), 64);
      }
#pragma unroll
      for (int i = 0; i < 4; i++){
        unsigned short* orow = attnO + (size_t)(b * S_LEN + q0 + lk*4 + i) * QSZ + h * HD + lq;
#pragma unroll
        for (int db = 0; db < 16; db++){
          float v = oacc[db][i] * sc0[i]
                  + obuf[hh * 4096 + (lk*4 + i) * 256 + db*16 + lq] * sc1[i];
          orow[db * 16] = f2bf(v);
        }
      }
    }
    __syncthreads();                             // obuf/Ks free before next item's stage
  }
#undef STAGE_K2
#undef STAGE_V2
}

extern "C" void kernel_launch(void* const* d_in, const int* in_sizes, int n_in,
                              void* d_out, int out_size, void* d_ws, size_t ws_size,
                              hipStream_t stream)
{
  const int*   positions = (const int*)  d_in[0];
  const float* hidden    = (const float*)d_in[1];
  const int*   amask     = (const int*)  d_in[2];
  const float* Wqkv      = (const float*)d_in[3];
  const float* Wo        = (const float*)d_in[4];
  const float* qw        = (const float*)d_in[5];
  const float* kw        = (const float*)d_in[6];
  float* out = (float*)d_out;

  char* ws = (char*)d_ws;
  unsigned short* hB    = (unsigned short*)(ws);               // 4096x2560 bf16
  unsigned short* attnO = (unsigned short*)(ws);               // alias (4096x2048 bf16)
  unsigned short* WqT   = (unsigned short*)(ws + 20971520);    // [4096][2560] bf16
  unsigned short* WoT   = (unsigned short*)(ws + 41943040);    // [2560][2048] bf16
  unsigned short* qkvB  = (unsigned short*)(ws + 52428800);    // [4096][4096] bf16
  unsigned short* qb    = (unsigned short*)(ws + 119537664);   // [B][NH][S][HD]
  unsigned short* kb    = (unsigned short*)(ws + 136314880);   // [B][NKV][S][HD]
  unsigned short* vt    = (unsigned short*)(ws + 144703488);   // [B][NKV][HD][S]
  unsigned*       bm    = (unsigned*)     (ws + 153092096);   // [B][64] mask bits
  int*            ctr   = (int*)          (ws + 153092608);   // [8] work-queue counters

  cast_bf16_kernel<<<dim3(MROWS * HIDDEN / 1024), 256, 0, stream>>>(hidden, hB, MROWS * HIDDEN);
  tcast_kernel<<<dim3(NQKV / 32, HIDDEN / 32), 256, 0, stream>>>(Wqkv, WqT, HIDDEN, NQKV);
  tcast_kernel<<<dim3(HIDDEN / 32, QSZ / 32), 256, 0, stream>>>(Wo, WoT, QSZ, HIDDEN);
  maskbits_kernel<<<dim3(1), 128, 0, stream>>>(amask, bm, ctr);

  // GEMM1: [4096 x 2560] * [2560 x 4096] -> qkvB (bf16); grid 256 blocks
  gemm256_kernel<1><<<dim3((MROWS/256) * (NQKV/256)), 512, 0, stream>>>(
      hB, WqT, qkvB, NQKV, HIDDEN, NQKV/256);

  normrope_kernel<<<dim3(S_LEN, BATCH), 256, 0, stream>>>(qkvB, positions, qw, kw, qb, kb, vt);

  attn_kernel<<<dim3(512), 256, 0, stream>>>(qb, kb, vt, bm, attnO, ctr);

  // GEMM2: [4096 x 2048] * [2048 x 2560] -> out (f32); grid 160 blocks
  gemm256_kernel<0><<<dim3((MROWS/256) * (HIDDEN/256)), 512, 0, stream>>>(
      attnO, WoT, out, HIDDEN, QSZ, HIDDEN/256);
}

// Round 11
// 336.366 us; speedup vs baseline: 1.4066x; 1.0770x over previous
//
#include <hip/hip_runtime.h>
#include <stdint.h>

#define S_LEN 2048
#define BATCH 2
#define HIDDEN 2560
#define NH 8
#define NKV 4
#define HD 256
#define QSZ (NH*HD)          // 2048
#define NQKV 4096            // QSZ + 2*KVSZ
#define MROWS (BATCH*S_LEN)  // 4096
#define SCALE_ATT 0.0625f

using bf16x8 = __attribute__((__ext_vector_type__(8))) __bf16;
using f32x4  = __attribute__((__ext_vector_type__(4))) float;
using s16x8  = __attribute__((__ext_vector_type__(8))) short;

union B8u { s16x8 s; bf16x8 b; };
union I4B8 { int4 i; bf16x8 b; };

__device__ __forceinline__ unsigned short f2bf(float x){
  unsigned u = __float_as_uint(x);
  u += 0x7fffu + ((u >> 16) & 1u);
  return (unsigned short)(u >> 16);
}
__device__ __forceinline__ float bf2f(unsigned short h){
  return __uint_as_float(((unsigned)h) << 16);
}
__device__ __forceinline__ bf16x8 ld_bf8(const unsigned short* p){
  B8u u; u.s = *reinterpret_cast<const s16x8*>(p); return u.b;
}
__device__ __forceinline__ f32x4 mfma16(bf16x8 a, bf16x8 b, f32x4 c){
  return __builtin_amdgcn_mfma_f32_16x16x32_bf16(a, b, c, 0, 0, 0);
}
__device__ __forceinline__ void gload16(const void* g, void* l){
  __builtin_amdgcn_global_load_lds((const __attribute__((address_space(1))) void*)g,
                                   (__attribute__((address_space(3))) void*)l,
                                   16, 0, 0);
}
__device__ __forceinline__ int cvtpk(float lo, float hi){
  int r;
  asm("v_cvt_pk_bf16_f32 %0, %1, %2" : "=v"(r) : "v"(lo), "v"(hi));
  return r;
}

// ---------------- cast fp32 -> bf16 (flat) ----------------
__global__ __launch_bounds__(256) void cast_bf16_kernel(
    const float* __restrict__ in, unsigned short* __restrict__ out, int n)
{
  int i = (blockIdx.x * 256 + threadIdx.x) * 4;
  if (i < n){
    float4 v = *reinterpret_cast<const float4*>(in + i);
    ushort4 o;
    o.x = f2bf(v.x); o.y = f2bf(v.y); o.z = f2bf(v.z); o.w = f2bf(v.w);
    *reinterpret_cast<ushort4*>(out + i) = o;
  }
}

// ---------------- transpose + cast: in[R][C] fp32 -> out[C][R] bf16 ----------------
__global__ __launch_bounds__(256) void tcast_kernel(
    const float* __restrict__ in, unsigned short* __restrict__ out, int R, int C)
{
  __shared__ float t[32][33];
  int c0 = blockIdx.x * 32, r0 = blockIdx.y * 32;
  int tx = threadIdx.x & 31, ty = threadIdx.x >> 5;
#pragma unroll
  for (int ii = 0; ii < 4; ii++)
    t[ty + ii*8][tx] = in[(size_t)(r0 + ty + ii*8) * C + c0 + tx];
  __syncthreads();
#pragma unroll
  for (int ii = 0; ii < 4; ii++)
    out[(size_t)(c0 + ty + ii*8) * R + r0 + tx] = f2bf(t[tx][ty + ii*8]);
}

// ================= 256x256 8-wave deep-pipelined GEMM (T2+T3+T4+T5) =================
template<int BF16OUT>
__global__ __launch_bounds__(512, 2) void gemm256_kernel(
    const unsigned short* __restrict__ A,
    const unsigned short* __restrict__ BT,
    void* __restrict__ Cv,
    int N, int K, int nbn)
{
  __shared__ unsigned short Ab[2][256 * 64];
  __shared__ unsigned short Bb[2][256 * 64];

  const int tid  = threadIdx.x;
  const int lane = tid & 63;
  const int wid  = tid >> 6;            // 0..7
  const int wm = wid >> 2, wn = wid & 3;
  const int lq = lane & 15, lk = lane >> 4;

  const int cpx = gridDim.x >> 3;
  const int wg  = (blockIdx.x & 7) * cpx + (blockIdx.x >> 3);
  const int bm = wg / nbn, bn = wg % nbn;

  const int l8 = lane >> 3;
  const int sl = ((lane & 7) ^ l8) * 8;
  const unsigned short* agS = A  + (size_t)(bm*256 + wid*16 + l8) * K + sl;
  const unsigned short* bgS = BT + (size_t)(bn*256 + wid*16 + l8) * K + sl;

  f32x4 acc[4][4][2] = {};
  bf16x8 a[4][2], b[2][2];

#define STA(c, h, tt) do {                                                    \
    unsigned short* d = &Ab[c][(h)*8192 + wid*1024];                          \
    const unsigned short* s = agS + (size_t)(h)*128*K + (size_t)(tt)*64;      \
    gload16(s, d); gload16(s + 8*(size_t)K, d + 512);                         \
  } while (0)
#define STB(c, h, tt) do {                                                    \
    unsigned short* d = &Bb[c][(h)*8192 + wid*1024];                          \
    const unsigned short* s = bgS + (size_t)(h)*128*K + (size_t)(tt)*64;      \
    gload16(s, d); gload16(s + 8*(size_t)K, d + 512);                         \
  } while (0)
#define LDA(qa) do {                                                          \
    _Pragma("unroll") for (int m = 0; m < 4; m++)                             \
    _Pragma("unroll") for (int kk = 0; kk < 2; kk++)                          \
      a[m][kk] = ld_bf8(&Ab[cur][((qa)*128 + wm*64 + m*16 + lq)*64            \
                                 + (((kk*4 + lk) ^ (lq & 7)) << 3)]);         \
  } while (0)
#define LDB(qb) do {                                                          \
    _Pragma("unroll") for (int n = 0; n < 2; n++)                             \
    _Pragma("unroll") for (int kk = 0; kk < 2; kk++)                          \
      b[n][kk] = ld_bf8(&Bb[cur][((qb)*128 + wn*32 + n*16 + lq)*64            \
                                 + (((kk*4 + lk) ^ (lq & 7)) << 3)]);         \
  } while (0)
#define MM(qi) do {                                                           \
    __builtin_amdgcn_s_setprio(1);                                            \
    _Pragma("unroll") for (int m = 0; m < 4; m++)                             \
    _Pragma("unroll") for (int n = 0; n < 2; n++)                             \
    _Pragma("unroll") for (int kk = 0; kk < 2; kk++)                          \
      acc[qi][m][n] = mfma16(a[m][kk], b[n][kk], acc[qi][m][n]);              \
    __builtin_amdgcn_s_setprio(0);                                            \
  } while (0)
#define BARR __builtin_amdgcn_s_barrier()
#define VM(n) asm volatile("s_waitcnt vmcnt(" #n ")" ::: "memory")

  STA(0, 0, 0); STB(0, 0, 0); STB(0, 1, 0); STA(0, 1, 0);
  VM(4); BARR;

  const int NT = K >> 6;
  for (int t = 0; t < NT - 1; ++t){
    const int cur = t & 1, nxt = cur ^ 1;
    LDA(0); LDB(0); STA(nxt, 0, t+1);
    BARR; MM(0); VM(4); BARR;
    LDB(1);         STB(nxt, 0, t+1);
    BARR; MM(1); VM(4); BARR;
    LDA(1);         STB(nxt, 1, t+1);
    BARR; MM(2);        BARR;
    LDB(0);         STA(nxt, 1, t+1);
    BARR; MM(3); VM(4); BARR;
  }
  {
    const int cur = (NT - 1) & 1;
    LDA(0); LDB(0); BARR; MM(0); VM(2); BARR;
    LDB(1);         BARR; MM(1); VM(0); BARR;
    LDA(1);         BARR; MM(2);        BARR;
    LDB(0);         BARR; MM(3);        BARR;
  }
#undef STA
#undef STB
#undef LDA
#undef LDB
#undef MM
#undef BARR
#undef VM

#pragma unroll
  for (int qi = 0; qi < 4; qi++){
    const int qa = qi >> 1;
    const int qb = (qi ^ (qi >> 1)) & 1;
    const int r0 = bm*256 + qa*128 + wm*64;
    const int c0 = bn*256 + qb*128 + wn*32;
#pragma unroll
    for (int m = 0; m < 4; m++)
#pragma unroll
      for (int n = 0; n < 2; n++)
#pragma unroll
        for (int i = 0; i < 4; i++){
          const size_t idx = (size_t)(r0 + m*16 + lk*4 + i) * N + (c0 + n*16 + lq);
          if (BF16OUT) ((unsigned short*)Cv)[idx] = f2bf(acc[qi][m][n][i]);
          else         ((float*)Cv)[idx]          = acc[qi][m][n][i];
        }
  }
}

// ---------------- RMSNorm + RoPE + scatter to q/k/vT (qkv bf16) ----------------
__global__ __launch_bounds__(256) void normrope_kernel(
    const unsigned short* __restrict__ qkv,
    const int* __restrict__ positions,
    const float* __restrict__ qw, const float* __restrict__ kw,
    unsigned short* __restrict__ qB,
    unsigned short* __restrict__ kB,
    unsigned short* __restrict__ vT)
{
  const int s = blockIdx.x, b = blockIdx.y;
  const int lane = threadIdx.x & 63, wid = threadIdx.x >> 6;
  const unsigned short* row = qkv + (size_t)(b * S_LEN + s) * NQKV;
  const float fpos = (float)positions[b * S_LEN + s];

#pragma unroll
  for (int t = 0; t < 4; t++){
    const int seg = t * 4 + wid;
    const int base = seg * HD;
    float x0 = bf2f(row[base + lane]);
    float x1 = bf2f(row[base + lane + 64]);
    float x2 = bf2f(row[base + lane + 128]);
    float x3 = bf2f(row[base + lane + 192]);
    if (seg >= 12){
      const int mh = seg - 12;
      unsigned short* vb = vT + (size_t)(b * NKV + mh) * HD * S_LEN + s;
      vb[(size_t)(lane      ) * S_LEN] = f2bf(x0);
      vb[(size_t)(lane +  64) * S_LEN] = f2bf(x1);
      vb[(size_t)(lane + 128) * S_LEN] = f2bf(x2);
      vb[(size_t)(lane + 192) * S_LEN] = f2bf(x3);
    } else {
      const float* w = (seg < 8) ? qw : kw;
      float ssq = x0*x0 + x1*x1 + x2*x2 + x3*x3;
#pragma unroll
      for (int d = 1; d < 64; d <<= 1) ssq += __shfl_xor(ssq, d, 64);
      float rs = rsqrtf(ssq * (1.0f / 256.0f) + 1e-6f);
      float y0 = x0 * rs * (1.0f + w[lane]);
      float y1 = x1 * rs * (1.0f + w[lane + 64]);
      float y2 = x2 * rs * (1.0f + w[lane + 128]);
      float y3 = x3 * rs * (1.0f + w[lane + 192]);
      const float kln = -9.210340371976184f / 128.0f;
      float inv1 = expf((float)lane * kln);
      float inv2 = expf((float)(lane + 64) * kln);
      float s1, c1, s2, c2;
      sincosf(fpos * inv1, &s1, &c1);
      sincosf(fpos * inv2, &s2, &c2);
      float o0 = y0 * c1 - y2 * s1;
      float o2 = y2 * c1 + y0 * s1;
      float o1 = y1 * c2 - y3 * s2;
      float o3 = y3 * c2 + y1 * s2;
      unsigned short* dst = (seg < 8)
        ? qB + ((size_t)(b * NH  +  seg     ) * S_LEN + s) * HD
        : kB + ((size_t)(b * NKV + (seg - 8)) * S_LEN + s) * HD;
      dst[lane      ] = f2bf(o0);
      dst[lane +  64] = f2bf(o1);
      dst[lane + 128] = f2bf(o2);
      dst[lane + 192] = f2bf(o3);
    }
  }
}

// ---------------- mask bit pack + work-queue counter reset ----------------
__global__ void maskbits_kernel(const int* __restrict__ amask, unsigned* __restrict__ bm,
                                int* __restrict__ ctr)
{
  int t = threadIdx.x;                 // 0..127
  int b = t >> 6, tile = t & 63;
  unsigned m = 0;
  for (int j = 0; j < 32; j++)
    m |= (amask[b * S_LEN + tile * 32 + j] != 0 ? 1u : 0u) << j;
  bm[t] = m;
  if (t < 8) ctr[t] = 0;
}

// ---------------- flash attention v10: R8 structure + paired 64-key iterations ----------------
// Grid 256 (1 block/CU), per-combo queue (64 items of 32 q-rows, heavy-first) — all as R8.
// NEW: each iteration consumes TWO 32-key tiles (4-deep LDS buffers, 128KB); the two
// QK/PV chains are independent (in-wave ILP) and softmax fuses over 64 keys with a
// single defer-check + 2 shfl-reduces -> serial iteration count halves (2080 -> 1056).
__global__ __launch_bounds__(256) void attn_kernel(
    const unsigned short* __restrict__ qB,
    const unsigned short* __restrict__ kB,
    const unsigned short* __restrict__ vT,
    const unsigned* __restrict__ bmG,
    unsigned short* __restrict__ attnO,
    int* __restrict__ ctr)
{
  __shared__ unsigned short Kb[4][32 * 256];   // [tile&3][key][d-granule ^ (key&7)]
  __shared__ unsigned short Vb[4][256 * 32];   // [tile&3][d][key-chunk swz]
  __shared__ unsigned bm_lds[64];
  __shared__ int s_idx;

  const int tid  = threadIdx.x;
  const int lane = tid & 63, wid = tid >> 6;
  const int c  = blockIdx.x & 7;
  const int mh = c & 3, b = c >> 2;
  const int h  = mh * 2 + (wid >> 1);
  const int lq = lane & 15, lk = lane >> 4;

  if (tid < 64) bm_lds[tid] = bmG[(b << 6) + tid];

  const unsigned short* kbase = kB + (size_t)(b * NKV + mh) * S_LEN * HD;
  const unsigned short* vbase = vT + (size_t)(b * NKV + mh) * HD * S_LEN;
  const int krow0 = wid * 2 + (lane >> 5);
  const int kgsrc = (lane & 31) ^ (krow0 & 7);
  const unsigned short* kg0 = kbase + (size_t)krow0 * HD + kgsrc * 8;
  const int vd0 = wid * 16 + (lane >> 2);
  const int vgsrc = (lane & 3) ^ ((lane >> 3) & 3);
  const unsigned short* vg0 = vbase + (size_t)vd0 * S_LEN + vgsrc * 8;

#define STAGE_K(buf, ktv)                                                      \
  do {                                                                         \
    _Pragma("unroll")                                                          \
    for (int r = 0; r < 4; r++)                                                \
      gload16(kg0 + (size_t)(ktv) * HD + r * (8 * HD),                         \
              &Kb[buf][wid * 512 + r * 2048]);                                 \
  } while (0)
#define STAGE_V(buf, ktv)                                                      \
  do {                                                                         \
    _Pragma("unroll")                                                          \
    for (int r = 0; r < 4; r++)                                                \
      gload16(vg0 + (ktv) + (size_t)r * (64 * S_LEN),                          \
              &Vb[buf][wid * 512 + r * 2048]);                                 \
  } while (0)

  for (;;){
    if (tid == 0) s_idx = atomicAdd(&ctr[c], 1);
    __syncthreads();
    const int idx = s_idx;
    __syncthreads();
    if (idx >= 64) break;
    const int qt = 63 - idx;                     // heavy-first

    const int q0 = qt * 32 + (wid & 1) * 16;
    const int q  = q0 + lq;

    const unsigned short* qbase = qB + ((size_t)(b * NH + h) * S_LEN + q0 + lq) * HD + lk * 8;
    bf16x8 aq[8];
#pragma unroll
    for (int ks = 0; ks < 8; ks++) aq[ks] = ld_bf8(qbase + ks * 32);
    asm volatile("s_waitcnt vmcnt(0)" ::: "memory");   // drain Q + epilogue stores

    float mi = -__builtin_inff(), li = 0.f;
    f32x4 oacc[16] = {};

    // prologue: stage tiles 0..min(qt,3)
    STAGE_K(0, 0); STAGE_V(0, 0);
    if (qt >= 1){ STAGE_K(1, 32); STAGE_V(1, 32); }
    if (qt >= 2){ STAGE_K(2, 64); STAGE_V(2, 64); }
    if (qt >= 3){ STAGE_K(3, 96); STAGE_V(3, 96); }

    const int npairs = (qt >> 1) + 1;
    for (int p = 0; p < npairs; ++p){
      const int ktA = p * 64;
      const int ktB = ktA + 32;
      const bool hasB = (2*p + 1 <= qt);
      const int bufA = (2*p) & 3, bufB = (2*p + 1) & 3;

      const int ahead = qt - 2*p - 1;            // tiles staged beyond this pair
      if (ahead >= 2)      asm volatile("s_waitcnt vmcnt(16)" ::: "memory");
      else if (ahead == 1) asm volatile("s_waitcnt vmcnt(8)"  ::: "memory");
      else                 asm volatile("s_waitcnt vmcnt(0)"  ::: "memory");
      __syncthreads();                           // (A) pair buffers published

      // ---- swapped QK^T for both tiles (4 independent chains) ----
      f32x4 sA0 = {0.f,0.f,0.f,0.f}, sA1 = {0.f,0.f,0.f,0.f};
      f32x4 sB0 = {0.f,0.f,0.f,0.f}, sB1 = {0.f,0.f,0.f,0.f};
      if (hasB){
#pragma unroll
        for (int ks = 0; ks < 8; ks++){
          const int slot = (((ks * 4 + lk) ^ (lq & 7)) << 3);
          bf16x8 kA0 = ld_bf8(&Kb[bufA][lq * 256 + slot]);
          bf16x8 kA1 = ld_bf8(&Kb[bufA][(16 + lq) * 256 + slot]);
          bf16x8 kB0 = ld_bf8(&Kb[bufB][lq * 256 + slot]);
          bf16x8 kB1 = ld_bf8(&Kb[bufB][(16 + lq) * 256 + slot]);
          sA0 = mfma16(kA0, aq[ks], sA0);
          sA1 = mfma16(kA1, aq[ks], sA1);
          sB0 = mfma16(kB0, aq[ks], sB0);
          sB1 = mfma16(kB1, aq[ks], sB1);
        }
      } else {
#pragma unroll
        for (int ks = 0; ks < 8; ks++){
          const int slot = (((ks * 4 + lk) ^ (lq & 7)) << 3);
          bf16x8 kA0 = ld_bf8(&Kb[bufA][lq * 256 + slot]);
          bf16x8 kA1 = ld_bf8(&Kb[bufA][(16 + lq) * 256 + slot]);
          sA0 = mfma16(kA0, aq[ks], sA0);
          sA1 = mfma16(kA1, aq[ks], sA1);
        }
      }

      // ---- fused online softmax over up to 64 keys ----
      const unsigned mA = bm_lds[ktA >> 5];
      const unsigned mB = bm_lds[(ktB >> 5) & 63];
      const int koff = lk * 4;
      float vA0[4], vA1[4], vB0[4], vB1[4];
#pragma unroll
      for (int j2 = 0; j2 < 4; j2++){
        const bool a0 = (ktA + koff + j2 <= q)      && ((mA >> (koff + j2)) & 1u);
        const bool a1 = (ktA + 16 + koff + j2 <= q) && ((mA >> (16 + koff + j2)) & 1u);
        vA0[j2] = a0 ? sA0[j2] * SCALE_ATT : -__builtin_inff();
        vA1[j2] = a1 ? sA1[j2] * SCALE_ATT : -__builtin_inff();
      }
      if (hasB){
#pragma unroll
        for (int j2 = 0; j2 < 4; j2++){
          const bool b0 = (ktB + koff + j2 <= q)      && ((mB >> (koff + j2)) & 1u);
          const bool b1 = (ktB + 16 + koff + j2 <= q) && ((mB >> (16 + koff + j2)) & 1u);
          vB0[j2] = b0 ? sB0[j2] * SCALE_ATT : -__builtin_inff();
          vB1[j2] = b1 ? sB1[j2] * SCALE_ATT : -__builtin_inff();
        }
      } else {
#pragma unroll
        for (int j2 = 0; j2 < 4; j2++){ vB0[j2] = -__builtin_inff(); vB1[j2] = -__builtin_inff(); }
      }
      float tm = fmaxf(fmaxf(fmaxf(vA0[0], vA0[1]), fmaxf(vA0[2], vA0[3])),
                       fmaxf(fmaxf(vA1[0], vA1[1]), fmaxf(vA1[2], vA1[3])));
      if (hasB){
        float tb = fmaxf(fmaxf(fmaxf(vB0[0], vB0[1]), fmaxf(vB0[2], vB0[3])),
                         fmaxf(fmaxf(vB1[0], vB1[1]), fmaxf(vB1[2], vB1[3])));
        tm = fmaxf(tm, tb);
      }
      tm = fmaxf(tm, __shfl_xor(tm, 16, 64));
      tm = fmaxf(tm, __shfl_xor(tm, 32, 64));

      float pA0[4], pA1[4], pB0[4], pB1[4];
      if (__all(tm <= mi + 8.0f)){
        const float mns = fmaxf(mi, -1e30f);
#pragma unroll
        for (int j2 = 0; j2 < 4; j2++){
          pA0[j2] = __expf(vA0[j2] - mns); pA1[j2] = __expf(vA1[j2] - mns);
          pB0[j2] = __expf(vB0[j2] - mns); pB1[j2] = __expf(vB1[j2] - mns);
        }
        float rs = (pA0[0]+pA0[1])+(pA0[2]+pA0[3])+(pA1[0]+pA1[1])+(pA1[2]+pA1[3])
                 + (pB0[0]+pB0[1])+(pB0[2]+pB0[3])+(pB1[0]+pB1[1])+(pB1[2]+pB1[3]);
        rs += __shfl_xor(rs, 16, 64);
        rs += __shfl_xor(rs, 32, 64);
        li += rs;
      } else {
        const float mn  = fmaxf(mi, tm);
        const float mns = fmaxf(mn, -1e30f);
#pragma unroll
        for (int j2 = 0; j2 < 4; j2++){
          pA0[j2] = __expf(vA0[j2] - mns); pA1[j2] = __expf(vA1[j2] - mns);
          pB0[j2] = __expf(vB0[j2] - mns); pB1[j2] = __expf(vB1[j2] - mns);
        }
        const float a_ = __expf(mi - mns);
        float rs = (pA0[0]+pA0[1])+(pA0[2]+pA0[3])+(pA1[0]+pA1[1])+(pA1[2]+pA1[3])
                 + (pB0[0]+pB0[1])+(pB0[2]+pB0[3])+(pB1[0]+pB1[1])+(pB1[2]+pB1[3]);
        rs += __shfl_xor(rs, 16, 64);
        rs += __shfl_xor(rs, 32, 64);
        li = li * a_ + rs;
        mi = mn;
        float av[4];
#pragma unroll
        for (int i = 0; i < 4; i++)
          av[i] = __shfl(a_, (lane & 48) | (lk * 4 + i), 64);
#pragma unroll
        for (int db = 0; db < 16; db++){
          f32x4 o = oacc[db];
#pragma unroll
          for (int i = 0; i < 4; i++) o[i] *= av[i];
          oacc[db] = o;
        }
      }

      // ---- redistribute P -> PV A-fragments (both tiles, independent) ----
      const int sA_ = (((lk & 1) * 2) << 4) | lq;
      const int sB_ = sA_ + 16;
      const bool hi = (lk >= 2);
      I4B8 pauA, pauB;
      {
        const int w0 = cvtpk(pA0[0], pA0[1]), w1 = cvtpk(pA0[2], pA0[3]);
        const int w2 = cvtpk(pA1[0], pA1[1]), w3 = cvtpk(pA1[2], pA1[3]);
        const int a0 = __shfl(w0, sA_, 64), a1 = __shfl(w1, sA_, 64);
        const int b0 = __shfl(w0, sB_, 64), b1 = __shfl(w1, sB_, 64);
        const int c0w = __shfl(w2, sA_, 64), c1w = __shfl(w3, sA_, 64);
        const int d0w = __shfl(w2, sB_, 64), d1w = __shfl(w3, sB_, 64);
        pauA.i.x = hi ? c0w : a0;
        pauA.i.y = hi ? c1w : a1;
        pauA.i.z = hi ? d0w : b0;
        pauA.i.w = hi ? d1w : b1;
      }
      if (hasB){
        const int w0 = cvtpk(pB0[0], pB0[1]), w1 = cvtpk(pB0[2], pB0[3]);
        const int w2 = cvtpk(pB1[0], pB1[1]), w3 = cvtpk(pB1[2], pB1[3]);
        const int a0 = __shfl(w0, sA_, 64), a1 = __shfl(w1, sA_, 64);
        const int b0 = __shfl(w0, sB_, 64), b1 = __shfl(w1, sB_, 64);
        const int c0w = __shfl(w2, sA_, 64), c1w = __shfl(w3, sA_, 64);
        const int d0w = __shfl(w2, sB_, 64), d1w = __shfl(w3, sB_, 64);
        pauB.i.x = hi ? c0w : a0;
        pauB.i.y = hi ? c1w : a1;
        pauB.i.z = hi ? d0w : b0;
        pauB.i.w = hi ? d1w : b1;
      }

      // ---- PV for both tiles ----
      const int vslot = (lk ^ ((lq >> 1) & 3)) << 3;
      if (hasB){
#pragma unroll
        for (int db = 0; db < 16; db++){
          bf16x8 vfA = ld_bf8(&Vb[bufA][(db * 16 + lq) * 32 + vslot]);
          bf16x8 vfB = ld_bf8(&Vb[bufB][(db * 16 + lq) * 32 + vslot]);
          f32x4 o = mfma16(pauA.b, vfA, oacc[db]);
          oacc[db] = mfma16(pauB.b, vfB, o);
        }
      } else {
#pragma unroll
        for (int db = 0; db < 16; db++){
          bf16x8 vfA = ld_bf8(&Vb[bufA][(db * 16 + lq) * 32 + vslot]);
          oacc[db] = mfma16(pauA.b, vfA, oacc[db]);
        }
      }

      __syncthreads();                           // (B) all waves done with pair buffers
      if (2*p + 4 <= qt){ STAGE_K(bufA, ktA + 128); STAGE_V(bufA, ktA + 128); }
      if (2*p + 5 <= qt){ STAGE_K(bufB, ktB + 128); STAGE_V(bufB, ktB + 128); }
    }

    // ---- epilogue ----
#pragma unroll
    for (int i = 0; i < 4; i++){
      const float lf = __shfl(li, (lane & 48) | (lk * 4 + i), 64);
      const float inv = 1.0f / lf;
      unsigned short* orow = attnO + (size_t)(b * S_LEN + q0 + lk*4 + i) * QSZ + h * HD + lq;
#pragma unroll
      for (int db = 0; db < 16; db++)
        orow[db * 16] = f2bf(oacc[db][i] * inv);
    }
  }
#undef STAGE_K
#undef STAGE_V
}

extern "C" void kernel_launch(void* const* d_in, const int* in_sizes, int n_in,
                              void* d_out, int out_size, void* d_ws, size_t ws_size,
                              hipStream_t stream)
{
  const int*   positions = (const int*)  d_in[0];
  const float* hidden    = (const float*)d_in[1];
  const int*   amask     = (const int*)  d_in[2];
  const float* Wqkv      = (const float*)d_in[3];
  const float* Wo        = (const float*)d_in[4];
  const float* qw        = (const float*)d_in[5];
  const float* kw        = (const float*)d_in[6];
  float* out = (float*)d_out;

  char* ws = (char*)d_ws;
  unsigned short* hB    = (unsigned short*)(ws);               // 4096x2560 bf16
  unsigned short* attnO = (unsigned short*)(ws);               // alias (4096x2048 bf16)
  unsigned short* WqT   = (unsigned short*)(ws + 20971520);    // [4096][2560] bf16
  unsigned short* WoT   = (unsigned short*)(ws + 41943040);    // [2560][2048] bf16
  unsigned short* qkvB  = (unsigned short*)(ws + 52428800);    // [4096][4096] bf16
  unsigned short* qb    = (unsigned short*)(ws + 119537664);   // [B][NH][S][HD]
  unsigned short* kb    = (unsigned short*)(ws + 136314880);   // [B][NKV][S][HD]
  unsigned short* vt    = (unsigned short*)(ws + 144703488);   // [B][NKV][HD][S]
  unsigned*       bm    = (unsigned*)     (ws + 153092096);   // [B][64] mask bits
  int*            ctr   = (int*)          (ws + 153092608);   // [8] work-queue counters

  cast_bf16_kernel<<<dim3(MROWS * HIDDEN / 1024), 256, 0, stream>>>(hidden, hB, MROWS * HIDDEN);
  tcast_kernel<<<dim3(NQKV / 32, HIDDEN / 32), 256, 0, stream>>>(Wqkv, WqT, HIDDEN, NQKV);
  tcast_kernel<<<dim3(HIDDEN / 32, QSZ / 32), 256, 0, stream>>>(Wo, WoT, QSZ, HIDDEN);
  maskbits_kernel<<<dim3(1), 128, 0, stream>>>(amask, bm, ctr);

  // GEMM1: [4096 x 2560] * [2560 x 4096] -> qkvB (bf16); grid 256 blocks
  gemm256_kernel<1><<<dim3((MROWS/256) * (NQKV/256)), 512, 0, stream>>>(
      hB, WqT, qkvB, NQKV, HIDDEN, NQKV/256);

  normrope_kernel<<<dim3(S_LEN, BATCH), 256, 0, stream>>>(qkvB, positions, qw, kw, qb, kb, vt);

  attn_kernel<<<dim3(256), 256, 0, stream>>>(qb, kb, vt, bm, attnO, ctr);

  // GEMM2: [4096 x 2048] * [2048 x 2560] -> out (f32); grid 160 blocks
  gemm256_kernel<0><<<dim3((MROWS/256) * (HIDDEN/256)), 512, 0, stream>>>(
      attnO, WoT, out, HIDDEN, QSZ, HIDDEN/256);
}

// Round 12
// 317.679 us; speedup vs baseline: 1.4893x; 1.0588x over previous
//
#include <hip/hip_runtime.h>
#include <stdint.h>

#define S_LEN 2048
#define BATCH 2
#define HIDDEN 2560
#define NH 8
#define NKV 4
#define HD 256
#define QSZ (NH*HD)          // 2048
#define NQKV 4096            // QSZ + 2*KVSZ
#define MROWS (BATCH*S_LEN)  // 4096
#define SCALE_ATT 0.0625f

using bf16x8 = __attribute__((__ext_vector_type__(8))) __bf16;
using f32x4  = __attribute__((__ext_vector_type__(4))) float;
using s16x8  = __attribute__((__ext_vector_type__(8))) short;

union B8u { s16x8 s; bf16x8 b; };
union I4B8 { int4 i; bf16x8 b; };

__device__ __forceinline__ unsigned short f2bf(float x){
  unsigned u = __float_as_uint(x);
  u += 0x7fffu + ((u >> 16) & 1u);
  return (unsigned short)(u >> 16);
}
__device__ __forceinline__ bf16x8 ld_bf8(const unsigned short* p){
  B8u u; u.s = *reinterpret_cast<const s16x8*>(p); return u.b;
}
__device__ __forceinline__ f32x4 mfma16(bf16x8 a, bf16x8 b, f32x4 c){
  return __builtin_amdgcn_mfma_f32_16x16x32_bf16(a, b, c, 0, 0, 0);
}
__device__ __forceinline__ void gload16(const void* g, void* l){
  __builtin_amdgcn_global_load_lds((const __attribute__((address_space(1))) void*)g,
                                   (__attribute__((address_space(3))) void*)l,
                                   16, 0, 0);
}
__device__ __forceinline__ int cvtpk(float lo, float hi){
  int r;
  asm("v_cvt_pk_bf16_f32 %0, %1, %2" : "=v"(r) : "v"(lo), "v"(hi));
  return r;
}

// ---------------- cast fp32 -> bf16 (flat) ----------------
__global__ __launch_bounds__(256) void cast_bf16_kernel(
    const float* __restrict__ in, unsigned short* __restrict__ out, int n)
{
  int i = (blockIdx.x * 256 + threadIdx.x) * 4;
  if (i < n){
    float4 v = *reinterpret_cast<const float4*>(in + i);
    ushort4 o;
    o.x = f2bf(v.x); o.y = f2bf(v.y); o.z = f2bf(v.z); o.w = f2bf(v.w);
    *reinterpret_cast<ushort4*>(out + i) = o;
  }
}

// ---------------- transpose + cast: in[R][C] fp32 -> out[C][R] bf16 ----------------
__global__ __launch_bounds__(256) void tcast_kernel(
    const float* __restrict__ in, unsigned short* __restrict__ out, int R, int C)
{
  __shared__ float t[32][33];
  int c0 = blockIdx.x * 32, r0 = blockIdx.y * 32;
  int tx = threadIdx.x & 31, ty = threadIdx.x >> 5;
#pragma unroll
  for (int ii = 0; ii < 4; ii++)
    t[ty + ii*8][tx] = in[(size_t)(r0 + ty + ii*8) * C + c0 + tx];
  __syncthreads();
#pragma unroll
  for (int ii = 0; ii < 4; ii++)
    out[(size_t)(c0 + ty + ii*8) * R + r0 + tx] = f2bf(t[tx][ty + ii*8]);
}

// ---------------- RoPE cos/sin tables: [b][c(128)][s(2048)] f32 ----------------
__global__ __launch_bounds__(256) void ropetab_kernel(
    const int* __restrict__ positions, float* __restrict__ ct, float* __restrict__ st)
{
  const int cix = blockIdx.x;        // 0..127
  const int b   = blockIdx.y;        // 0..1
  const float kln = -9.210340371976184f / 128.0f;   // -ln(10000)/128
  const float inv = expf((float)cix * kln);
  float* cp = ct + ((size_t)b * 128 + cix) * 2048;
  float* sp = st + ((size_t)b * 128 + cix) * 2048;
  for (int s = threadIdx.x; s < S_LEN; s += 256){
    float fpos = (float)positions[b * S_LEN + s];
    float sv, cv;
    sincosf(fpos * inv, &sv, &cv);
    cp[s] = cv;
    sp[s] = sv;
  }
}

// ================= GEMM1 fused: 256x256 8-wave pipelined + RMSNorm/RoPE epilogue =====
// C-tile col range = exactly one head (BN=256=HD). Writes qB/kB (normed+roped bf16)
// and vT (transposed bf16) directly — no qkv intermediate, no normrope kernel.
__global__ __launch_bounds__(512, 2) void gemm_qkv_kernel(
    const unsigned short* __restrict__ A,
    const unsigned short* __restrict__ BT,
    const float* __restrict__ qw, const float* __restrict__ kw,
    const float* __restrict__ ct, const float* __restrict__ st,
    unsigned short* __restrict__ qB,
    unsigned short* __restrict__ kB,
    unsigned short* __restrict__ vT)
{
  __shared__ unsigned short Ab[2][256 * 64];
  __shared__ unsigned short Bb[2][256 * 64];

  const int K = HIDDEN;
  const int nbn = 16;
  const int tid  = threadIdx.x;
  const int lane = tid & 63;
  const int wid  = tid >> 6;
  const int wm = wid >> 2, wn = wid & 3;
  const int lq = lane & 15, lk = lane >> 4;

  const int cpx = gridDim.x >> 3;
  const int wg  = (blockIdx.x & 7) * cpx + (blockIdx.x >> 3);
  const int bm = wg / nbn, bn = wg % nbn;

  const int l8 = lane >> 3;
  const int sl = ((lane & 7) ^ l8) * 8;
  const unsigned short* agS = A  + (size_t)(bm*256 + wid*16 + l8) * K + sl;
  const unsigned short* bgS = BT + (size_t)(bn*256 + wid*16 + l8) * K + sl;

  f32x4 acc[4][4][2] = {};
  bf16x8 a[4][2], b[2][2];

#define STA(c, h, tt) do {                                                    \
    unsigned short* d = &Ab[c][(h)*8192 + wid*1024];                          \
    const unsigned short* s = agS + (size_t)(h)*128*K + (size_t)(tt)*64;      \
    gload16(s, d); gload16(s + 8*(size_t)K, d + 512);                         \
  } while (0)
#define STB(c, h, tt) do {                                                    \
    unsigned short* d = &Bb[c][(h)*8192 + wid*1024];                          \
    const unsigned short* s = bgS + (size_t)(h)*128*K + (size_t)(tt)*64;      \
    gload16(s, d); gload16(s + 8*(size_t)K, d + 512);                         \
  } while (0)
#define LDA(qa) do {                                                          \
    _Pragma("unroll") for (int m = 0; m < 4; m++)                             \
    _Pragma("unroll") for (int kk = 0; kk < 2; kk++)                          \
      a[m][kk] = ld_bf8(&Ab[cur][((qa)*128 + wm*64 + m*16 + lq)*64            \
                                 + (((kk*4 + lk) ^ (lq & 7)) << 3)]);         \
  } while (0)
#define LDB(qb) do {                                                          \
    _Pragma("unroll") for (int n = 0; n < 2; n++)                             \
    _Pragma("unroll") for (int kk = 0; kk < 2; kk++)                          \
      b[n][kk] = ld_bf8(&Bb[cur][((qb)*128 + wn*32 + n*16 + lq)*64            \
                                 + (((kk*4 + lk) ^ (lq & 7)) << 3)]);         \
  } while (0)
#define MM(qi) do {                                                           \
    __builtin_amdgcn_s_setprio(1);                                            \
    _Pragma("unroll") for (int m = 0; m < 4; m++)                             \
    _Pragma("unroll") for (int n = 0; n < 2; n++)                             \
    _Pragma("unroll") for (int kk = 0; kk < 2; kk++)                          \
      acc[qi][m][n] = mfma16(a[m][kk], b[n][kk], acc[qi][m][n]);              \
    __builtin_amdgcn_s_setprio(0);                                            \
  } while (0)
#define BARR __builtin_amdgcn_s_barrier()
#define VM(n) asm volatile("s_waitcnt vmcnt(" #n ")" ::: "memory")

  STA(0, 0, 0); STB(0, 0, 0); STB(0, 1, 0); STA(0, 1, 0);
  VM(4); BARR;

  const int NT = K >> 6;
  for (int t = 0; t < NT - 1; ++t){
    const int cur = t & 1, nxt = cur ^ 1;
    LDA(0); LDB(0); STA(nxt, 0, t+1);
    BARR; MM(0); VM(4); BARR;
    LDB(1);         STB(nxt, 0, t+1);
    BARR; MM(1); VM(4); BARR;
    LDA(1);         STB(nxt, 1, t+1);
    BARR; MM(2);        BARR;
    LDB(0);         STA(nxt, 1, t+1);
    BARR; MM(3); VM(4); BARR;
  }
  {
    const int cur = (NT - 1) & 1;
    LDA(0); LDB(0); BARR; MM(0); VM(2); BARR;
    LDB(1);         BARR; MM(1); VM(0); BARR;
    LDA(1);         BARR; MM(2);        BARR;
    LDB(0);         BARR; MM(3);        BARR;
  }
#undef STA
#undef STB
#undef LDA
#undef LDB
#undef MM
#undef BARR
#undef VM

  // ---------- fused epilogue ----------
  // qi -> (qa, qb): 0:(0,0) 1:(0,1) 2:(1,1) 3:(1,0)
  __syncthreads();                                 // LDS free for reuse
  const int b_  = bm >> 3;                         // batch
  const int sb0 = (bm & 7) * 256;                  // batch-local s base of block

  if (bn >= 12){
    // ---- V heads: transposed bf16 store, no norm/rope ----
    const int mhv = bn - 12;
#pragma unroll
    for (int qi = 0; qi < 4; qi++){
      const int qa = qi >> 1, qb = (qi ^ (qi >> 1)) & 1;
#pragma unroll
      for (int m = 0; m < 4; m++){
        const int s0 = sb0 + qa*128 + wm*64 + m*16 + lk*4;
#pragma unroll
        for (int n = 0; n < 2; n++){
          const int d = qb*128 + wn*32 + n*16 + lq;
          ushort4 o;
          o.x = f2bf(acc[qi][m][n][0]);
          o.y = f2bf(acc[qi][m][n][1]);
          o.z = f2bf(acc[qi][m][n][2]);
          o.w = f2bf(acc[qi][m][n][3]);
          *reinterpret_cast<ushort4*>(
              vT + ((size_t)((b_*NKV + mhv)*HD + d))*S_LEN + s0) = o;
        }
      }
    }
  } else {
    // ---- Q/K heads: RMSNorm (block-local reduce) + RoPE (in-lane pairs) ----
    float* red = (float*)Ab;                       // [4 wn][256 rows]
    float part[2][4][4];
#pragma unroll
    for (int qa = 0; qa < 2; qa++){
      const int qiA = qa ? 3 : 0, qiB = qa ? 2 : 1;
#pragma unroll
      for (int m = 0; m < 4; m++)
#pragma unroll
      for (int i = 0; i < 4; i++){
        float s = 0.f;
#pragma unroll
        for (int n = 0; n < 2; n++)
          s += acc[qiA][m][n][i]*acc[qiA][m][n][i]
             + acc[qiB][m][n][i]*acc[qiB][m][n][i];
        s += __shfl_xor(s, 1, 64);
        s += __shfl_xor(s, 2, 64);
        s += __shfl_xor(s, 4, 64);
        s += __shfl_xor(s, 8, 64);
        part[qa][m][i] = s;
      }
    }
    if (lq == 0){
#pragma unroll
      for (int qa = 0; qa < 2; qa++)
#pragma unroll
      for (int m = 0; m < 4; m++)
#pragma unroll
      for (int i = 0; i < 4; i++)
        red[wn*256 + qa*128 + wm*64 + m*16 + lk*4 + i] = part[qa][m][i];
    }
    __syncthreads();
    float rsv[2][4][4];
#pragma unroll
    for (int qa = 0; qa < 2; qa++)
#pragma unroll
    for (int m = 0; m < 4; m++)
#pragma unroll
    for (int i = 0; i < 4; i++){
      const int row = qa*128 + wm*64 + m*16 + lk*4 + i;
      float tt = red[row] + red[256 + row] + red[512 + row] + red[768 + row];
      rsv[qa][m][i] = rsqrtf(tt * (1.0f/256.0f) + 1e-6f);
    }
    const float* wv = (bn < 8) ? qw : kw;
    unsigned short* dstB = (bn < 8)
      ? qB + ((size_t)(b_*NH  + bn      ) * S_LEN) * HD
      : kB + ((size_t)(b_*NKV + (bn - 8)) * S_LEN) * HD;
    const float* ctb = ct + (size_t)b_ * 128 * 2048;
    const float* stb = st + (size_t)b_ * 128 * 2048;
#pragma unroll
    for (int qa = 0; qa < 2; qa++){
      const int qiA = qa ? 3 : 0, qiB = qa ? 2 : 1;
#pragma unroll
      for (int m = 0; m < 4; m++){
        const int s0 = sb0 + qa*128 + wm*64 + m*16 + lk*4;
#pragma unroll
        for (int n = 0; n < 2; n++){
          const int c0 = wn*32 + n*16 + lq;
          const float w0 = 1.0f + wv[c0];
          const float w1 = 1.0f + wv[c0 + 128];
          const float4 c4 = *reinterpret_cast<const float4*>(ctb + (size_t)c0*2048 + s0);
          const float4 s4 = *reinterpret_cast<const float4*>(stb + (size_t)c0*2048 + s0);
#pragma unroll
          for (int i = 0; i < 4; i++){
            const float rs_ = rsv[qa][m][i];
            const float y0 = acc[qiA][m][n][i] * rs_ * w0;
            const float y1 = acc[qiB][m][n][i] * rs_ * w1;
            const float cc = (&c4.x)[i], ss = (&s4.x)[i];
            unsigned short* p = dstB + (size_t)(s0 + i) * HD;
            p[c0]       = f2bf(y0 * cc - y1 * ss);
            p[c0 + 128] = f2bf(y1 * cc + y0 * ss);
          }
        }
      }
    }
  }
}

// ================= 256x256 8-wave deep-pipelined GEMM (f32 out, for GEMM2) ==========
__global__ __launch_bounds__(512, 2) void gemm256_kernel(
    const unsigned short* __restrict__ A,
    const unsigned short* __restrict__ BT,
    float* __restrict__ C,
    int N, int K, int nbn)
{
  __shared__ unsigned short Ab[2][256 * 64];
  __shared__ unsigned short Bb[2][256 * 64];

  const int tid  = threadIdx.x;
  const int lane = tid & 63;
  const int wid  = tid >> 6;
  const int wm = wid >> 2, wn = wid & 3;
  const int lq = lane & 15, lk = lane >> 4;

  const int cpx = gridDim.x >> 3;
  const int wg  = (blockIdx.x & 7) * cpx + (blockIdx.x >> 3);
  const int bm = wg / nbn, bn = wg % nbn;

  const int l8 = lane >> 3;
  const int sl = ((lane & 7) ^ l8) * 8;
  const unsigned short* agS = A  + (size_t)(bm*256 + wid*16 + l8) * K + sl;
  const unsigned short* bgS = BT + (size_t)(bn*256 + wid*16 + l8) * K + sl;

  f32x4 acc[4][4][2] = {};
  bf16x8 a[4][2], b[2][2];

#define STA(c, h, tt) do {                                                    \
    unsigned short* d = &Ab[c][(h)*8192 + wid*1024];                          \
    const unsigned short* s = agS + (size_t)(h)*128*K + (size_t)(tt)*64;      \
    gload16(s, d); gload16(s + 8*(size_t)K, d + 512);                         \
  } while (0)
#define STB(c, h, tt) do {                                                    \
    unsigned short* d = &Bb[c][(h)*8192 + wid*1024];                          \
    const unsigned short* s = bgS + (size_t)(h)*128*K + (size_t)(tt)*64;      \
    gload16(s, d); gload16(s + 8*(size_t)K, d + 512);                         \
  } while (0)
#define LDA(qa) do {                                                          \
    _Pragma("unroll") for (int m = 0; m < 4; m++)                             \
    _Pragma("unroll") for (int kk = 0; kk < 2; kk++)                          \
      a[m][kk] = ld_bf8(&Ab[cur][((qa)*128 + wm*64 + m*16 + lq)*64            \
                                 + (((kk*4 + lk) ^ (lq & 7)) << 3)]);         \
  } while (0)
#define LDB(qb) do {                                                          \
    _Pragma("unroll") for (int n = 0; n < 2; n++)                             \
    _Pragma("unroll") for (int kk = 0; kk < 2; kk++)                          \
      b[n][kk] = ld_bf8(&Bb[cur][((qb)*128 + wn*32 + n*16 + lq)*64            \
                                 + (((kk*4 + lk) ^ (lq & 7)) << 3)]);         \
  } while (0)
#define MM(qi) do {                                                           \
    __builtin_amdgcn_s_setprio(1);                                            \
    _Pragma("unroll") for (int m = 0; m < 4; m++)                             \
    _Pragma("unroll") for (int n = 0; n < 2; n++)                             \
    _Pragma("unroll") for (int kk = 0; kk < 2; kk++)                          \
      acc[qi][m][n] = mfma16(a[m][kk], b[n][kk], acc[qi][m][n]);              \
    __builtin_amdgcn_s_setprio(0);                                            \
  } while (0)
#define BARR __builtin_amdgcn_s_barrier()
#define VM(n) asm volatile("s_waitcnt vmcnt(" #n ")" ::: "memory")

  STA(0, 0, 0); STB(0, 0, 0); STB(0, 1, 0); STA(0, 1, 0);
  VM(4); BARR;

  const int NT = K >> 6;
  for (int t = 0; t < NT - 1; ++t){
    const int cur = t & 1, nxt = cur ^ 1;
    LDA(0); LDB(0); STA(nxt, 0, t+1);
    BARR; MM(0); VM(4); BARR;
    LDB(1);         STB(nxt, 0, t+1);
    BARR; MM(1); VM(4); BARR;
    LDA(1);         STB(nxt, 1, t+1);
    BARR; MM(2);        BARR;
    LDB(0);         STA(nxt, 1, t+1);
    BARR; MM(3); VM(4); BARR;
  }
  {
    const int cur = (NT - 1) & 1;
    LDA(0); LDB(0); BARR; MM(0); VM(2); BARR;
    LDB(1);         BARR; MM(1); VM(0); BARR;
    LDA(1);         BARR; MM(2);        BARR;
    LDB(0);         BARR; MM(3);        BARR;
  }
#undef STA
#undef STB
#undef LDA
#undef LDB
#undef MM
#undef BARR
#undef VM

#pragma unroll
  for (int qi = 0; qi < 4; qi++){
    const int qa = qi >> 1;
    const int qb = (qi ^ (qi >> 1)) & 1;
    const int r0 = bm*256 + qa*128 + wm*64;
    const int c0 = bn*256 + qb*128 + wn*32;
#pragma unroll
    for (int m = 0; m < 4; m++)
#pragma unroll
      for (int n = 0; n < 2; n++)
#pragma unroll
        for (int i = 0; i < 4; i++)
          C[(size_t)(r0 + m*16 + lk*4 + i) * N + (c0 + n*16 + lq)] = acc[qi][m][n][i];
  }
}

// ---------------- mask bit pack + work-queue counter reset ----------------
__global__ void maskbits_kernel(const int* __restrict__ amask, unsigned* __restrict__ bm,
                                int* __restrict__ ctr)
{
  int t = threadIdx.x;                 // 0..127
  int b = t >> 6, tile = t & 63;
  unsigned m = 0;
  for (int j = 0; j < 32; j++)
    m |= (amask[b * S_LEN + tile * 32 + j] != 0 ? 1u : 0u) << j;
  bm[t] = m;
  if (t < 8) ctr[t] = 0;
}

// ---------------- flash attention (R11): paired 64-key iterations, work queue ----------------
__global__ __launch_bounds__(256) void attn_kernel(
    const unsigned short* __restrict__ qB,
    const unsigned short* __restrict__ kB,
    const unsigned short* __restrict__ vT,
    const unsigned* __restrict__ bmG,
    unsigned short* __restrict__ attnO,
    int* __restrict__ ctr)
{
  __shared__ unsigned short Kb[4][32 * 256];
  __shared__ unsigned short Vb[4][256 * 32];
  __shared__ unsigned bm_lds[64];
  __shared__ int s_idx;

  const int tid  = threadIdx.x;
  const int lane = tid & 63, wid = tid >> 6;
  const int c  = blockIdx.x & 7;
  const int mh = c & 3, b = c >> 2;
  const int h  = mh * 2 + (wid >> 1);
  const int lq = lane & 15, lk = lane >> 4;

  if (tid < 64) bm_lds[tid] = bmG[(b << 6) + tid];

  const unsigned short* kbase = kB + (size_t)(b * NKV + mh) * S_LEN * HD;
  const unsigned short* vbase = vT + (size_t)(b * NKV + mh) * HD * S_LEN;
  const int krow0 = wid * 2 + (lane >> 5);
  const int kgsrc = (lane & 31) ^ (krow0 & 7);
  const unsigned short* kg0 = kbase + (size_t)krow0 * HD + kgsrc * 8;
  const int vd0 = wid * 16 + (lane >> 2);
  const int vgsrc = (lane & 3) ^ ((lane >> 3) & 3);
  const unsigned short* vg0 = vbase + (size_t)vd0 * S_LEN + vgsrc * 8;

#define STAGE_K(buf, ktv)                                                      \
  do {                                                                         \
    _Pragma("unroll")                                                          \
    for (int r = 0; r < 4; r++)                                                \
      gload16(kg0 + (size_t)(ktv) * HD + r * (8 * HD),                         \
              &Kb[buf][wid * 512 + r * 2048]);                                 \
  } while (0)
#define STAGE_V(buf, ktv)                                                      \
  do {                                                                         \
    _Pragma("unroll")                                                          \
    for (int r = 0; r < 4; r++)                                                \
      gload16(vg0 + (ktv) + (size_t)r * (64 * S_LEN),                          \
              &Vb[buf][wid * 512 + r * 2048]);                                 \
  } while (0)

  for (;;){
    if (tid == 0) s_idx = atomicAdd(&ctr[c], 1);
    __syncthreads();
    const int idx = s_idx;
    __syncthreads();
    if (idx >= 64) break;
    const int qt = 63 - idx;

    const int q0 = qt * 32 + (wid & 1) * 16;
    const int q  = q0 + lq;

    const unsigned short* qbase = qB + ((size_t)(b * NH + h) * S_LEN + q0 + lq) * HD + lk * 8;
    bf16x8 aq[8];
#pragma unroll
    for (int ks = 0; ks < 8; ks++) aq[ks] = ld_bf8(qbase + ks * 32);
    asm volatile("s_waitcnt vmcnt(0)" ::: "memory");

    float mi = -__builtin_inff(), li = 0.f;
    f32x4 oacc[16] = {};

    STAGE_K(0, 0); STAGE_V(0, 0);
    if (qt >= 1){ STAGE_K(1, 32); STAGE_V(1, 32); }
    if (qt >= 2){ STAGE_K(2, 64); STAGE_V(2, 64); }
    if (qt >= 3){ STAGE_K(3, 96); STAGE_V(3, 96); }

    const int npairs = (qt >> 1) + 1;
    for (int p = 0; p < npairs; ++p){
      const int ktA = p * 64;
      const int ktB = ktA + 32;
      const bool hasB = (2*p + 1 <= qt);
      const int bufA = (2*p) & 3, bufB = (2*p + 1) & 3;

      const int ahead = qt - 2*p - 1;
      if (ahead >= 2)      asm volatile("s_waitcnt vmcnt(16)" ::: "memory");
      else if (ahead == 1) asm volatile("s_waitcnt vmcnt(8)"  ::: "memory");
      else                 asm volatile("s_waitcnt vmcnt(0)"  ::: "memory");
      __syncthreads();

      f32x4 sA0 = {0.f,0.f,0.f,0.f}, sA1 = {0.f,0.f,0.f,0.f};
      f32x4 sB0 = {0.f,0.f,0.f,0.f}, sB1 = {0.f,0.f,0.f,0.f};
      if (hasB){
#pragma unroll
        for (int ks = 0; ks < 8; ks++){
          const int slot = (((ks * 4 + lk) ^ (lq & 7)) << 3);
          bf16x8 kA0 = ld_bf8(&Kb[bufA][lq * 256 + slot]);
          bf16x8 kA1 = ld_bf8(&Kb[bufA][(16 + lq) * 256 + slot]);
          bf16x8 kB0 = ld_bf8(&Kb[bufB][lq * 256 + slot]);
          bf16x8 kB1 = ld_bf8(&Kb[bufB][(16 + lq) * 256 + slot]);
          sA0 = mfma16(kA0, aq[ks], sA0);
          sA1 = mfma16(kA1, aq[ks], sA1);
          sB0 = mfma16(kB0, aq[ks], sB0);
          sB1 = mfma16(kB1, aq[ks], sB1);
        }
      } else {
#pragma unroll
        for (int ks = 0; ks < 8; ks++){
          const int slot = (((ks * 4 + lk) ^ (lq & 7)) << 3);
          bf16x8 kA0 = ld_bf8(&Kb[bufA][lq * 256 + slot]);
          bf16x8 kA1 = ld_bf8(&Kb[bufA][(16 + lq) * 256 + slot]);
          sA0 = mfma16(kA0, aq[ks], sA0);
          sA1 = mfma16(kA1, aq[ks], sA1);
        }
      }

      const unsigned mA = bm_lds[ktA >> 5];
      const unsigned mB = bm_lds[(ktB >> 5) & 63];
      const int koff = lk * 4;
      float vA0[4], vA1[4], vB0[4], vB1[4];
#pragma unroll
      for (int j2 = 0; j2 < 4; j2++){
        const bool a0 = (ktA + koff + j2 <= q)      && ((mA >> (koff + j2)) & 1u);
        const bool a1 = (ktA + 16 + koff + j2 <= q) && ((mA >> (16 + koff + j2)) & 1u);
        vA0[j2] = a0 ? sA0[j2] * SCALE_ATT : -__builtin_inff();
        vA1[j2] = a1 ? sA1[j2] * SCALE_ATT : -__builtin_inff();
      }
      if (hasB){
#pragma unroll
        for (int j2 = 0; j2 < 4; j2++){
          const bool b0 = (ktB + koff + j2 <= q)      && ((mB >> (koff + j2)) & 1u);
          const bool b1 = (ktB + 16 + koff + j2 <= q) && ((mB >> (16 + koff + j2)) & 1u);
          vB0[j2] = b0 ? sB0[j2] * SCALE_ATT : -__builtin_inff();
          vB1[j2] = b1 ? sB1[j2] * SCALE_ATT : -__builtin_inff();
        }
      } else {
#pragma unroll
        for (int j2 = 0; j2 < 4; j2++){ vB0[j2] = -__builtin_inff(); vB1[j2] = -__builtin_inff(); }
      }
      float tm = fmaxf(fmaxf(fmaxf(vA0[0], vA0[1]), fmaxf(vA0[2], vA0[3])),
                       fmaxf(fmaxf(vA1[0], vA1[1]), fmaxf(vA1[2], vA1[3])));
      if (hasB){
        float tb = fmaxf(fmaxf(fmaxf(vB0[0], vB0[1]), fmaxf(vB0[2], vB0[3])),
                         fmaxf(fmaxf(vB1[0], vB1[1]), fmaxf(vB1[2], vB1[3])));
        tm = fmaxf(tm, tb);
      }
      tm = fmaxf(tm, __shfl_xor(tm, 16, 64));
      tm = fmaxf(tm, __shfl_xor(tm, 32, 64));

      float pA0[4], pA1[4], pB0[4], pB1[4];
      if (__all(tm <= mi + 8.0f)){
        const float mns = fmaxf(mi, -1e30f);
#pragma unroll
        for (int j2 = 0; j2 < 4; j2++){
          pA0[j2] = __expf(vA0[j2] - mns); pA1[j2] = __expf(vA1[j2] - mns);
          pB0[j2] = __expf(vB0[j2] - mns); pB1[j2] = __expf(vB1[j2] - mns);
        }
        float rs = (pA0[0]+pA0[1])+(pA0[2]+pA0[3])+(pA1[0]+pA1[1])+(pA1[2]+pA1[3])
                 + (pB0[0]+pB0[1])+(pB0[2]+pB0[3])+(pB1[0]+pB1[1])+(pB1[2]+pB1[3]);
        rs += __shfl_xor(rs, 16, 64);
        rs += __shfl_xor(rs, 32, 64);
        li += rs;
      } else {
        const float mn  = fmaxf(mi, tm);
        const float mns = fmaxf(mn, -1e30f);
#pragma unroll
        for (int j2 = 0; j2 < 4; j2++){
          pA0[j2] = __expf(vA0[j2] - mns); pA1[j2] = __expf(vA1[j2] - mns);
          pB0[j2] = __expf(vB0[j2] - mns); pB1[j2] = __expf(vB1[j2] - mns);
        }
        const float a_ = __expf(mi - mns);
        float rs = (pA0[0]+pA0[1])+(pA0[2]+pA0[3])+(pA1[0]+pA1[1])+(pA1[2]+pA1[3])
                 + (pB0[0]+pB0[1])+(pB0[2]+pB0[3])+(pB1[0]+pB1[1])+(pB1[2]+pB1[3]);
        rs += __shfl_xor(rs, 16, 64);
        rs += __shfl_xor(rs, 32, 64);
        li = li * a_ + rs;
        mi = mn;
        float av[4];
#pragma unroll
        for (int i = 0; i < 4; i++)
          av[i] = __shfl(a_, (lane & 48) | (lk * 4 + i), 64);
#pragma unroll
        for (int db = 0; db < 16; db++){
          f32x4 o = oacc[db];
#pragma unroll
          for (int i = 0; i < 4; i++) o[i] *= av[i];
          oacc[db] = o;
        }
      }

      const int sA_ = (((lk & 1) * 2) << 4) | lq;
      const int sB_ = sA_ + 16;
      const bool hi = (lk >= 2);
      I4B8 pauA, pauB;
      {
        const int w0 = cvtpk(pA0[0], pA0[1]), w1 = cvtpk(pA0[2], pA0[3]);
        const int w2 = cvtpk(pA1[0], pA1[1]), w3 = cvtpk(pA1[2], pA1[3]);
        const int a0 = __shfl(w0, sA_, 64), a1 = __shfl(w1, sA_, 64);
        const int b0 = __shfl(w0, sB_, 64), b1 = __shfl(w1, sB_, 64);
        const int c0w = __shfl(w2, sA_, 64), c1w = __shfl(w3, sA_, 64);
        const int d0w = __shfl(w2, sB_, 64), d1w = __shfl(w3, sB_, 64);
        pauA.i.x = hi ? c0w : a0;
        pauA.i.y = hi ? c1w : a1;
        pauA.i.z = hi ? d0w : b0;
        pauA.i.w = hi ? d1w : b1;
      }
      if (hasB){
        const int w0 = cvtpk(pB0[0], pB0[1]), w1 = cvtpk(pB0[2], pB0[3]);
        const int w2 = cvtpk(pB1[0], pB1[1]), w3 = cvtpk(pB1[2], pB1[3]);
        const int a0 = __shfl(w0, sA_, 64), a1 = __shfl(w1, sA_, 64);
        const int b0 = __shfl(w0, sB_, 64), b1 = __shfl(w1, sB_, 64);
        const int c0w = __shfl(w2, sA_, 64), c1w = __shfl(w3, sA_, 64);
        const int d0w = __shfl(w2, sB_, 64), d1w = __shfl(w3, sB_, 64);
        pauB.i.x = hi ? c0w : a0;
        pauB.i.y = hi ? c1w : a1;
        pauB.i.z = hi ? d0w : b0;
        pauB.i.w = hi ? d1w : b1;
      }

      const int vslot = (lk ^ ((lq >> 1) & 3)) << 3;
      if (hasB){
#pragma unroll
        for (int db = 0; db < 16; db++){
          bf16x8 vfA = ld_bf8(&Vb[bufA][(db * 16 + lq) * 32 + vslot]);
          bf16x8 vfB = ld_bf8(&Vb[bufB][(db * 16 + lq) * 32 + vslot]);
          f32x4 o = mfma16(pauA.b, vfA, oacc[db]);
          oacc[db] = mfma16(pauB.b, vfB, o);
        }
      } else {
#pragma unroll
        for (int db = 0; db < 16; db++){
          bf16x8 vfA = ld_bf8(&Vb[bufA][(db * 16 + lq) * 32 + vslot]);
          oacc[db] = mfma16(pauA.b, vfA, oacc[db]);
        }
      }

      __syncthreads();
      if (2*p + 4 <= qt){ STAGE_K(bufA, ktA + 128); STAGE_V(bufA, ktA + 128); }
      if (2*p + 5 <= qt){ STAGE_K(bufB, ktB + 128); STAGE_V(bufB, ktB + 128); }
    }

#pragma unroll
    for (int i = 0; i < 4; i++){
      const float lf = __shfl(li, (lane & 48) | (lk * 4 + i), 64);
      const float inv = 1.0f / lf;
      unsigned short* orow = attnO + (size_t)(b * S_LEN + q0 + lk*4 + i) * QSZ + h * HD + lq;
#pragma unroll
      for (int db = 0; db < 16; db++)
        orow[db * 16] = f2bf(oacc[db][i] * inv);
    }
  }
#undef STAGE_K
#undef STAGE_V
}

extern "C" void kernel_launch(void* const* d_in, const int* in_sizes, int n_in,
                              void* d_out, int out_size, void* d_ws, size_t ws_size,
                              hipStream_t stream)
{
  const int*   positions = (const int*)  d_in[0];
  const float* hidden    = (const float*)d_in[1];
  const int*   amask     = (const int*)  d_in[2];
  const float* Wqkv      = (const float*)d_in[3];
  const float* Wo        = (const float*)d_in[4];
  const float* qw        = (const float*)d_in[5];
  const float* kw        = (const float*)d_in[6];
  float* out = (float*)d_out;

  char* ws = (char*)d_ws;
  unsigned short* hB    = (unsigned short*)(ws);               // 4096x2560 bf16
  unsigned short* attnO = (unsigned short*)(ws);               // alias (4096x2048 bf16)
  unsigned short* WqT   = (unsigned short*)(ws + 20971520);    // [4096][2560] bf16
  unsigned short* WoT   = (unsigned short*)(ws + 41943040);    // [2560][2048] bf16
  float*          ct    = (float*)        (ws + 52428800);    // [B][128][2048] cos
  float*          st    = (float*)        (ws + 56623104);    // [B][128][2048] sin
  unsigned short* qb    = (unsigned short*)(ws + 119537664);   // [B][NH][S][HD]
  unsigned short* kb    = (unsigned short*)(ws + 136314880);   // [B][NKV][S][HD]
  unsigned short* vt    = (unsigned short*)(ws + 144703488);   // [B][NKV][HD][S]
  unsigned*       bm    = (unsigned*)     (ws + 153092096);   // [B][64] mask bits
  int*            ctr   = (int*)          (ws + 153092608);   // [8] work-queue counters

  cast_bf16_kernel<<<dim3(MROWS * HIDDEN / 1024), 256, 0, stream>>>(hidden, hB, MROWS * HIDDEN);
  tcast_kernel<<<dim3(NQKV / 32, HIDDEN / 32), 256, 0, stream>>>(Wqkv, WqT, HIDDEN, NQKV);
  tcast_kernel<<<dim3(HIDDEN / 32, QSZ / 32), 256, 0, stream>>>(Wo, WoT, QSZ, HIDDEN);
  maskbits_kernel<<<dim3(1), 128, 0, stream>>>(amask, bm, ctr);
  ropetab_kernel<<<dim3(128, BATCH), 256, 0, stream>>>(positions, ct, st);

  // GEMM1 fused: [4096 x 2560] x [2560 x 4096] -> qb/kb/vt directly (norm+rope in epilogue)
  gemm_qkv_kernel<<<dim3((MROWS/256) * (NQKV/256)), 512, 0, stream>>>(
      hB, WqT, qw, kw, ct, st, qb, kb, vt);

  attn_kernel<<<dim3(256), 256, 0, stream>>>(qb, kb, vt, bm, attnO, ctr);

  // GEMM2: [4096 x 2048] * [2048 x 2560] -> out (f32); grid 160 blocks
  gemm256_kernel<<<dim3((MROWS/256) * (HIDDEN/256)), 512, 0, stream>>>(
      attnO, WoT, out, HIDDEN, QSZ, HIDDEN/256);
}